// Round 4
// baseline (322.507 us; speedup 1.0000x reference)
//
#include <hip/hip_runtime.h>
#include <math.h>

static constexpr int Bn = 8, Ln = 1024, Dm = 512, Hn = 8, DhN = 64;

typedef short bf16x8 __attribute__((ext_vector_type(8)));
typedef float f32x4 __attribute__((ext_vector_type(4)));
typedef _Float16 f16x4 __attribute__((ext_vector_type(4)));
typedef _Float16 f16x8 __attribute__((ext_vector_type(8)));

// 0.125 * log2(e): folding the 1/sqrt(dh) scale AND the exp->exp2 conversion
#define QSCALE 0.1803368801111137f

static __device__ __forceinline__ unsigned short f2b(float f) {
  union { float f; unsigned int u; } x;
  x.f = f;
  unsigned int u = x.u;
  unsigned int r = (u + 0x7FFFu + ((u >> 16) & 1u)) >> 16;  // RNE
  return (unsigned short)r;
}
static __device__ __forceinline__ float b2f(unsigned short u) {
  union { unsigned int u; float f; } x;
  x.u = ((unsigned int)u) << 16;
  return x.f;
}

#define GLDS16(g, l)                                                        \
  __builtin_amdgcn_global_load_lds((const __attribute__((address_space(1))) void*)(g), \
                                   (__attribute__((address_space(3))) void*)(l), 16, 0, 0)

// ---------------- LayerNorm -> bf16 ----------------
__global__ __launch_bounds__(256) void ln_kernel(const float* __restrict__ x,
                                                 const float* __restrict__ gamma,
                                                 const float* __restrict__ beta,
                                                 unsigned short* __restrict__ xn) {
  int row = blockIdx.x;
  int t = threadIdx.x;
  const float2 v = *(const float2*)(x + (size_t)row * Dm + t * 2);
  float s = v.x + v.y;
  float sq = v.x * v.x + v.y * v.y;
#pragma unroll
  for (int off = 32; off > 0; off >>= 1) {
    s += __shfl_down(s, off);
    sq += __shfl_down(sq, off);
  }
  __shared__ float red[8];
  int wave = t >> 6, lane = t & 63;
  if (lane == 0) { red[wave * 2] = s; red[wave * 2 + 1] = sq; }
  __syncthreads();
  float S = red[0] + red[2] + red[4] + red[6];
  float SQ = red[1] + red[3] + red[5] + red[7];
  float mu = S * (1.0f / Dm);
  float var = SQ * (1.0f / Dm) - mu * mu;
  float rstd = rsqrtf(var + 1e-5f);
  int c = t * 2;
  ushort2 o;
  o.x = f2b((v.x - mu) * rstd * gamma[c] + beta[c]);
  o.y = f2b((v.y - mu) * rstd * gamma[c + 1] + beta[c + 1]);
  *(ushort2*)(xn + (size_t)row * Dm + c) = o;
}

// ---------------- Sinusoidal pe[l][k] -> bf16 ----------------
__global__ __launch_bounds__(256) void pe_kernel(unsigned short* __restrict__ pe) {
  int idx = blockIdx.x * 256 + threadIdx.x;
  int l = idx >> 9, k = idx & 511;
  float freq = expf(-0.0359778921f * (float)k);
  float angle = (float)(l - k) * freq;
  pe[idx] = f2b((k & 1) ? sinf(angle) : cosf(angle));
}

// ---------------- f32 -> bf16 weight conversion ----------------
__global__ __launch_bounds__(256) void conv_kernel(const float* __restrict__ a,
                                                   unsigned short* __restrict__ b) {
  int i = blockIdx.x * 256 + threadIdx.x;
  float4 v = *(const float4*)(a + (size_t)i * 4);
  ushort4 o;
  o.x = f2b(v.x); o.y = f2b(v.y); o.z = f2b(v.z); o.w = f2b(v.w);
  *(ushort4*)(b + (size_t)i * 4) = o;
}

// ---------------- bf16 MFMA NT GEMM ----------------
// mode 0: scatter q (bf16, pre-scaled by QSCALE) / k (bf16) / v (fp16) in (B,H,L,Dh)
// mode 1: posb f32 (H,L,Dh); mode 2: outf f32 row-major.
__global__ __launch_bounds__(256) void gemm_mfma(const unsigned short* __restrict__ A,
                                                 const unsigned short* __restrict__ Bw,
                                                 const float* __restrict__ bias,
                                                 float* __restrict__ outf,
                                                 unsigned short* __restrict__ oq,
                                                 unsigned short* __restrict__ ok,
                                                 unsigned short* __restrict__ ov,
                                                 int M, int N, int K, int mode) {
  __shared__ alignas(16) unsigned short As[128 * 64];
  __shared__ alignas(16) unsigned short Bs[128 * 64];
  const int t = threadIdx.x;
  const int lane = t & 63, w = t >> 6;
  const int c = lane & 15, q8 = lane >> 4;
  const int wm = (w & 1) * 64, wn = (w >> 1) * 64;
  const int m0 = blockIdx.y * 128, n0 = blockIdx.x * 128;

  f32x4 acc[4][4];
#pragma unroll
  for (int i = 0; i < 4; ++i)
#pragma unroll
    for (int j = 0; j < 4; ++j) acc[i][j] = (f32x4){0.f, 0.f, 0.f, 0.f};

  const int srow = lane >> 3;
  const int scol = ((lane & 7) ^ srow) * 8;
  int arow[4];
#pragma unroll
  for (int j = 0; j < 4; ++j) arow[j] = w * 32 + j * 8 + srow;

  for (int k0 = 0; k0 < K; k0 += 64) {
    __syncthreads();
#pragma unroll
    for (int j = 0; j < 4; ++j) {
      GLDS16(A + (size_t)(m0 + arow[j]) * K + k0 + scol,
             As + ((w * 4 + j) * 64 + lane) * 8);
      GLDS16(Bw + (size_t)(n0 + arow[j]) * K + k0 + scol,
             Bs + ((w * 4 + j) * 64 + lane) * 8);
    }
    __syncthreads();
#pragma unroll
    for (int kk = 0; kk < 2; ++kk) {
      bf16x8 a[4], b[4];
      const int q = kk * 4 + q8;
#pragma unroll
      for (int i = 0; i < 4; ++i) {
        int r = wm + i * 16 + c;
        a[i] = *(const bf16x8*)&As[r * 64 + ((q ^ (r & 7)) * 8)];
      }
#pragma unroll
      for (int j = 0; j < 4; ++j) {
        int r = wn + j * 16 + c;
        b[j] = *(const bf16x8*)&Bs[r * 64 + ((q ^ (r & 7)) * 8)];
      }
#pragma unroll
      for (int i = 0; i < 4; ++i)
#pragma unroll
        for (int j = 0; j < 4; ++j)
          acc[i][j] = __builtin_amdgcn_mfma_f32_16x16x32_bf16(a[i], b[j], acc[i][j], 0, 0, 0);
    }
  }
#pragma unroll
  for (int i = 0; i < 4; ++i) {
#pragma unroll
    for (int r = 0; r < 4; ++r) {
      int m = m0 + wm + i * 16 + q8 * 4 + r;
#pragma unroll
      for (int j = 0; j < 4; ++j) {
        int n = n0 + wn + j * 16 + c;
        float val = acc[i][j][r] + (bias ? bias[n] : 0.0f);
        if (mode == 0) {
          int part = n >> 9, h = (n >> 6) & 7, dh = n & 63;
          int bb = m >> 10, l = m & 1023;
          size_t idx = (size_t)((bb * 8 + h) * 1024 + l) * 64 + dh;
          if (part == 0) {
            oq[idx] = f2b(val * QSCALE);
          } else if (part == 1) {
            ok[idx] = f2b(val);
          } else {
            union { _Float16 h; unsigned short u; } cv;
            cv.h = (_Float16)val;
            ov[idx] = cv.u;
          }
        } else if (mode == 1) {
          int h = n >> 6, dh = n & 63;
          outf[(size_t)(h * 1024 + m) * 64 + dh] = val;
        } else {
          outf[(size_t)m * N + n] = val;
        }
      }
    }
  }
}

// ---------------- Fold (in place): K' = k + pos[h] (bf16); bias = (u.k + vb.pos)*QSCALE ----------------
__global__ __launch_bounds__(256) void fold_kernel(unsigned short* __restrict__ kbuf,
                                                   const float* __restrict__ pos,
                                                   const float* __restrict__ ub,
                                                   const float* __restrict__ vbb,
                                                   float* __restrict__ biasout) {
  int t = threadIdx.x;
  int wave = t >> 6, lane = t & 63;
  int g = blockIdx.x * 4 + wave;  // [0, B*H*L)
  int h = (g >> 10) & 7;
  int m = g & 1023;
  float kv = b2f(kbuf[(size_t)g * 64 + lane]);
  float pv = pos[(size_t)(h * 1024 + m) * 64 + lane];
  float val = ub[h * 64 + lane] * kv + vbb[h * 64 + lane] * pv;
#pragma unroll
  for (int off = 32; off > 0; off >>= 1) val += __shfl_down(val, off);
  if (lane == 0) biasout[g] = val * QSCALE;
  kbuf[(size_t)g * 64 + lane] = f2b(kv + pv);
}

// ---------------- V fp16 (b,h,l,d) -> V2 fp16 (b,h,d,perm(l)) ----------------
// perm within each 64-block: dst = ((l>>2)&3)*16 + ((l>>4)&3)*4 + (l&3)
// so flash's x16 A-fragments (k = 4*q8+j) read 16 contiguous fp16 per (i, q8).
__global__ __launch_bounds__(256) void transv_kernel(const unsigned short* __restrict__ v,
                                                     unsigned short* __restrict__ vt) {
  __shared__ unsigned short Ts[64 * 68];
  int t = threadIdx.x;
  int bh = blockIdx.y, lt = blockIdx.x;
  const unsigned short* vg = v + (size_t)bh * 65536 + lt * 4096;
#pragma unroll
  for (int s = 0; s < 4; ++s) {
    int idx = t + s * 256;
    int r = idx >> 4, c4 = (idx & 15) << 2;
    *(ushort4*)&Ts[r * 68 + c4] = *(const ushort4*)(vg + r * 64 + c4);
  }
  __syncthreads();
#pragma unroll
  for (int s = 0; s < 4; ++s) {
    int idx = t + s * 256;
    int d = idx >> 4, l4 = (idx & 15) << 2;
    ushort4 o;
    o.x = Ts[(l4 + 0) * 68 + d];
    o.y = Ts[(l4 + 1) * 68 + d];
    o.z = Ts[(l4 + 2) * 68 + d];
    o.w = Ts[(l4 + 3) * 68 + d];
    int pb = ((l4 >> 2) & 3) * 16 + ((l4 >> 4) & 3) * 4;  // l4&3 == 0
    *(ushort4*)(vt + (size_t)bh * 65536 + d * 1024 + lt * 64 + pb) = o;
  }
}

// ---------------- Flash attention: S^T = K'.Q^T (bf16 x32), O^T = V^T.P^T (fp16 x16) ----------------
// No LDS, no barriers. grid (16, 64), 4 waves; wave w owns queries [16w, 16w+16).
// Lane (q8,c): sc[nt] reg r = S^T[key 16nt+4q8+r][query c] -- this IS the x16 B-fragment of P^T.
__global__ __launch_bounds__(256) void flash_mfma(const unsigned short* __restrict__ qbf,
                                                  const unsigned short* __restrict__ kbf,
                                                  const unsigned short* __restrict__ vt,
                                                  const float* __restrict__ bias,
                                                  unsigned short* __restrict__ attn_out) {
  const int t = threadIdx.x;
  const int lane = t & 63, w = t >> 6;
  const int c = lane & 15, q8 = lane >> 4;
  const int bh = blockIdx.y, qt = blockIdx.x;
  const unsigned short* qg = qbf + (size_t)bh * 65536;
  const unsigned short* kg = kbf + (size_t)bh * 65536;
  const unsigned short* vg = vt + (size_t)bh * 65536;
  const float* bg = bias + (size_t)bh * 1024;

  const int ql = qt * 64 + w * 16 + c;
  const bf16x8 bq0 = *(const bf16x8*)(qg + ql * 64 + q8 * 8);
  const bf16x8 bq1 = *(const bf16x8*)(qg + ql * 64 + 32 + q8 * 8);

  float m_st = -INFINITY, l_st = 0.0f;
  f32x4 o[4];
#pragma unroll
  for (int i = 0; i < 4; ++i) o[i] = (f32x4){0.f, 0.f, 0.f, 0.f};

  for (int kt = 0; kt < 16; ++kt) {
    // S^T with bias as MFMA C-initializer
    f32x4 sc[4];
#pragma unroll
    for (int nt = 0; nt < 4; ++nt) {
      f32x4 ci = *(const f32x4*)(bg + kt * 64 + nt * 16 + q8 * 4);
      const unsigned short* kr = kg + (size_t)(kt * 64 + nt * 16 + c) * 64 + q8 * 8;
      bf16x8 ak0 = *(const bf16x8*)kr;
      bf16x8 ak1 = *(const bf16x8*)(kr + 32);
      ci = __builtin_amdgcn_mfma_f32_16x16x32_bf16(ak0, bq0, ci, 0, 0, 0);
      sc[nt] = __builtin_amdgcn_mfma_f32_16x16x32_bf16(ak1, bq1, ci, 0, 0, 0);
    }
    // online softmax over keys (per-lane state for query c; reduce across q8 groups)
    float mx = sc[0][0];
#pragma unroll
    for (int nt = 0; nt < 4; ++nt)
#pragma unroll
      for (int r = 0; r < 4; ++r) mx = fmaxf(mx, sc[nt][r]);
    mx = fmaxf(mx, __shfl_xor(mx, 16));
    mx = fmaxf(mx, __shfl_xor(mx, 32));
    float mn = fmaxf(m_st, mx);
    float al = __builtin_amdgcn_exp2f(m_st - mn);
    float su = 0.0f;
    f16x4 pf[4];
#pragma unroll
    for (int nt = 0; nt < 4; ++nt)
#pragma unroll
      for (int r = 0; r < 4; ++r) {
        float p = __builtin_amdgcn_exp2f(sc[nt][r] - mn);
        su += p;
        pf[nt][r] = (_Float16)p;
      }
    su += __shfl_xor(su, 16);
    su += __shfl_xor(su, 32);
    l_st = l_st * al + su;
    m_st = mn;
#pragma unroll
    for (int i = 0; i < 4; ++i) o[i] *= al;
    // O^T += V^T . P^T  (x16 fp16; P straight from accumulators)
#pragma unroll
    for (int i = 0; i < 4; ++i) {
      const unsigned short* vr = vg + (size_t)(i * 16 + c) * 1024 + kt * 64 + q8 * 16;
      f16x8 v01 = *(const f16x8*)vr;
      f16x8 v23 = *(const f16x8*)(vr + 8);
      f16x4 a0 = {v01[0], v01[1], v01[2], v01[3]};
      f16x4 a1 = {v01[4], v01[5], v01[6], v01[7]};
      f16x4 a2 = {v23[0], v23[1], v23[2], v23[3]};
      f16x4 a3 = {v23[4], v23[5], v23[6], v23[7]};
      o[i] = __builtin_amdgcn_mfma_f32_16x16x16f16(a0, pf[0], o[i], 0, 0, 0);
      o[i] = __builtin_amdgcn_mfma_f32_16x16x16f16(a1, pf[1], o[i], 0, 0, 0);
      o[i] = __builtin_amdgcn_mfma_f32_16x16x16f16(a2, pf[2], o[i], 0, 0, 0);
      o[i] = __builtin_amdgcn_mfma_f32_16x16x16f16(a3, pf[3], o[i], 0, 0, 0);
    }
  }
  // epilogue: lane holds O^T[d = 16i+4q8+r][query c]
  const int bidx = bh >> 3, h = bh & 7;
  float inv = 1.0f / l_st;
  size_t base = (size_t)(bidx * 1024 + ql) * 512 + h * 64;
#pragma unroll
  for (int i = 0; i < 4; ++i) {
    ushort4 ov4;
    ov4.x = f2b(o[i][0] * inv);
    ov4.y = f2b(o[i][1] * inv);
    ov4.z = f2b(o[i][2] * inv);
    ov4.w = f2b(o[i][3] * inv);
    *(ushort4*)(attn_out + base + i * 16 + q8 * 4) = ov4;
  }
}

extern "C" void kernel_launch(void* const* d_in, const int* in_sizes, int n_in,
                              void* d_out, int out_size, void* d_ws, size_t ws_size,
                              hipStream_t stream) {
  const float* x      = (const float*)d_in[0];
  const float* gamma  = (const float*)d_in[1];
  const float* beta   = (const float*)d_in[2];
  const float* w_qkv  = (const float*)d_in[3];
  const float* b_qkv  = (const float*)d_in[4];
  const float* w_pos  = (const float*)d_in[5];
  const float* w_out  = (const float*)d_in[6];
  const float* b_out  = (const float*)d_in[7];
  const float* u_bias = (const float*)d_in[8];
  const float* v_bias = (const float*)d_in[9];
  float* out = (float*)d_out;

  unsigned short* wsu = (unsigned short*)d_ws;
  unsigned short* xnb   = wsu;                    // 4M ushort
  unsigned short* peb   = wsu + 4194304;          // 512K
  unsigned short* wqkvb = wsu + 4718592;          // 768K
  unsigned short* wposb = wsu + 5505024;          // 256K
  unsigned short* woutb = wsu + 5767168;          // 256K
  unsigned short* qbf   = wsu + 6291456;          // 4M (bf16, pre-scaled)
  unsigned short* kbf   = wsu + 10485760;         // 4M (K' bf16 after fold)
  unsigned short* vbf   = wsu + 14680064;         // 4M (fp16)
  unsigned short* vtb   = wsu + 18874368;         // 4M (fp16, permuted-transposed)
  unsigned short* attnb = wsu + 23068672;         // 4M (bf16)
  float* posb  = (float*)(wsu + 27262976);        // 512K floats
  float* biasb = (float*)(wsu + 28311552);        // 64K floats (pre-scaled)

  ln_kernel<<<8192, 256, 0, stream>>>(x, gamma, beta, xnb);
  pe_kernel<<<2048, 256, 0, stream>>>(peb);
  conv_kernel<<<768, 256, 0, stream>>>(w_qkv, wqkvb);
  conv_kernel<<<256, 256, 0, stream>>>(w_pos, wposb);
  conv_kernel<<<256, 256, 0, stream>>>(w_out, woutb);
  gemm_mfma<<<dim3(12, 64), 256, 0, stream>>>(xnb, wqkvb, b_qkv, nullptr, qbf, kbf, vbf,
                                              8192, 1536, 512, 0);
  gemm_mfma<<<dim3(4, 8), 256, 0, stream>>>(peb, wposb, nullptr, posb, nullptr, nullptr, nullptr,
                                            1024, 512, 512, 1);
  fold_kernel<<<16384, 256, 0, stream>>>(kbf, posb, u_bias, v_bias, biasb);
  transv_kernel<<<dim3(16, 64), 256, 0, stream>>>(vbf, vtb);
  flash_mfma<<<dim3(16, 64), 256, 0, stream>>>(qbf, kbf, vtb, biasb, attnb);
  gemm_mfma<<<dim3(4, 64), 256, 0, stream>>>(attnb, woutb, b_out, out, nullptr, nullptr, nullptr,
                                             8192, 512, 512, 2);
}

// Round 5
// 210.676 us; speedup vs baseline: 1.5308x; 1.5308x over previous
//
#include <hip/hip_runtime.h>
#include <math.h>

static constexpr int Bn = 8, Ln = 1024, Dm = 512, Hn = 8, DhN = 64;

typedef short bf16x8 __attribute__((ext_vector_type(8)));
typedef float f32x4 __attribute__((ext_vector_type(4)));
typedef _Float16 f16x4 __attribute__((ext_vector_type(4)));
typedef _Float16 f16x8 __attribute__((ext_vector_type(8)));

// 0.125 * log2(e): folds the 1/sqrt(dh) scale AND the exp->exp2 conversion
#define QSCALE 0.1803368801111137f

static __device__ __forceinline__ unsigned short f2b(float f) {
  union { float f; unsigned int u; } x;
  x.f = f;
  unsigned int u = x.u;
  unsigned int r = (u + 0x7FFFu + ((u >> 16) & 1u)) >> 16;  // RNE
  return (unsigned short)r;
}
static __device__ __forceinline__ float b2f(unsigned short u) {
  union { unsigned int u; float f; } x;
  x.u = ((unsigned int)u) << 16;
  return x.f;
}

#define GLDS16(g, l)                                                        \
  __builtin_amdgcn_global_load_lds((const __attribute__((address_space(1))) void*)(g), \
                                   (__attribute__((address_space(3))) void*)(l), 16, 0, 0)

// ---------------- prep1: LayerNorm + PE + weight conversions (one dispatch) ----------------
__global__ __launch_bounds__(256) void prep1(const float* __restrict__ x,
                                             const float* __restrict__ gamma,
                                             const float* __restrict__ beta,
                                             unsigned short* __restrict__ xn,
                                             unsigned short* __restrict__ pe,
                                             const float* __restrict__ wq, unsigned short* __restrict__ wqb,
                                             const float* __restrict__ wp, unsigned short* __restrict__ wpb,
                                             const float* __restrict__ wo, unsigned short* __restrict__ wob) {
  int b = blockIdx.x;
  int t = threadIdx.x;
  if (b < 8192) {
    // LayerNorm row b
    const float2 v = *(const float2*)(x + (size_t)b * Dm + t * 2);
    float s = v.x + v.y;
    float sq = v.x * v.x + v.y * v.y;
#pragma unroll
    for (int off = 32; off > 0; off >>= 1) {
      s += __shfl_down(s, off);
      sq += __shfl_down(sq, off);
    }
    __shared__ float red[8];
    int wave = t >> 6, lane = t & 63;
    if (lane == 0) { red[wave * 2] = s; red[wave * 2 + 1] = sq; }
    __syncthreads();
    float S = red[0] + red[2] + red[4] + red[6];
    float SQ = red[1] + red[3] + red[5] + red[7];
    float mu = S * (1.0f / Dm);
    float var = SQ * (1.0f / Dm) - mu * mu;
    float rstd = rsqrtf(var + 1e-5f);
    int c = t * 2;
    ushort2 o;
    o.x = f2b((v.x - mu) * rstd * gamma[c] + beta[c]);
    o.y = f2b((v.y - mu) * rstd * gamma[c + 1] + beta[c + 1]);
    *(ushort2*)(xn + (size_t)b * Dm + c) = o;
  } else if (b < 10240) {
    int idx = (b - 8192) * 256 + t;
    int l = idx >> 9, k = idx & 511;
    float freq = expf(-0.0359778921f * (float)k);
    float angle = (float)(l - k) * freq;
    pe[idx] = f2b((k & 1) ? sinf(angle) : cosf(angle));
  } else {
    int cb = b - 10240;  // 0..1279
    const float* src;
    unsigned short* dst;
    int off;
    if (cb < 768) { src = wq; dst = wqb; off = cb; }
    else if (cb < 1024) { src = wp; dst = wpb; off = cb - 768; }
    else { src = wo; dst = wob; off = cb - 1024; }
    int i = off * 256 + t;
    float4 v = *(const float4*)(src + (size_t)i * 4);
    ushort4 o;
    o.x = f2b(v.x); o.y = f2b(v.y); o.z = f2b(v.z); o.w = f2b(v.w);
    *(ushort4*)(dst + (size_t)i * 4) = o;
  }
}

// ---------------- bf16 MFMA NT GEMM (QKV + fused pos tile, or out) ----------------
// Blocks with blockIdx.y >= 64 run the small pos GEMM (A2/B2 -> outf2, mode 1).
// mode 0: scatter q (bf16, pre-scaled) / k (bf16) / v (fp16) in (B,H,L,Dh)
// mode 1: posb f32 (H,L,Dh); mode 2: outf f32 row-major (N=512).
__global__ __launch_bounds__(256) void gemm_mfma(const unsigned short* __restrict__ Ain,
                                                 const unsigned short* __restrict__ Bwin,
                                                 const float* __restrict__ biasin,
                                                 float* __restrict__ outfin,
                                                 unsigned short* __restrict__ oq,
                                                 unsigned short* __restrict__ ok,
                                                 unsigned short* __restrict__ ov,
                                                 const unsigned short* __restrict__ A2,
                                                 const unsigned short* __restrict__ B2,
                                                 float* __restrict__ outf2,
                                                 int K, int mode) {
  int by = blockIdx.y, bx = blockIdx.x;
  const unsigned short* A = Ain;
  const unsigned short* Bw = Bwin;
  const float* bias = biasin;
  float* outf = outfin;
  if (by >= 64) {
    if (bx >= 4) return;
    A = A2; Bw = B2; bias = nullptr; outf = outf2; mode = 1; by -= 64;
  }
  __shared__ alignas(16) unsigned short As[128 * 64];
  __shared__ alignas(16) unsigned short Bs[128 * 64];
  const int t = threadIdx.x;
  const int lane = t & 63, w = t >> 6;
  const int c = lane & 15, q8 = lane >> 4;
  const int wm = (w & 1) * 64, wn = (w >> 1) * 64;
  const int m0 = by * 128, n0 = bx * 128;

  f32x4 acc[4][4];
#pragma unroll
  for (int i = 0; i < 4; ++i)
#pragma unroll
    for (int j = 0; j < 4; ++j) acc[i][j] = (f32x4){0.f, 0.f, 0.f, 0.f};

  const int srow = lane >> 3;
  const int scol = ((lane & 7) ^ srow) * 8;
  int arow[4];
#pragma unroll
  for (int j = 0; j < 4; ++j) arow[j] = w * 32 + j * 8 + srow;

  for (int k0 = 0; k0 < K; k0 += 64) {
    __syncthreads();
#pragma unroll
    for (int j = 0; j < 4; ++j) {
      GLDS16(A + (size_t)(m0 + arow[j]) * K + k0 + scol,
             As + ((w * 4 + j) * 64 + lane) * 8);
      GLDS16(Bw + (size_t)(n0 + arow[j]) * K + k0 + scol,
             Bs + ((w * 4 + j) * 64 + lane) * 8);
    }
    __syncthreads();
#pragma unroll
    for (int kk = 0; kk < 2; ++kk) {
      bf16x8 a[4], b[4];
      const int q = kk * 4 + q8;
#pragma unroll
      for (int i = 0; i < 4; ++i) {
        int r = wm + i * 16 + c;
        a[i] = *(const bf16x8*)&As[r * 64 + ((q ^ (r & 7)) * 8)];
      }
#pragma unroll
      for (int j = 0; j < 4; ++j) {
        int r = wn + j * 16 + c;
        b[j] = *(const bf16x8*)&Bs[r * 64 + ((q ^ (r & 7)) * 8)];
      }
#pragma unroll
      for (int i = 0; i < 4; ++i)
#pragma unroll
        for (int j = 0; j < 4; ++j)
          acc[i][j] = __builtin_amdgcn_mfma_f32_16x16x32_bf16(a[i], b[j], acc[i][j], 0, 0, 0);
    }
  }
#pragma unroll
  for (int i = 0; i < 4; ++i) {
#pragma unroll
    for (int r = 0; r < 4; ++r) {
      int m = m0 + wm + i * 16 + q8 * 4 + r;
#pragma unroll
      for (int j = 0; j < 4; ++j) {
        int n = n0 + wn + j * 16 + c;
        float val = acc[i][j][r] + (bias ? bias[n] : 0.0f);
        if (mode == 0) {
          int part = n >> 9, h = (n >> 6) & 7, dh = n & 63;
          int bb = m >> 10, l = m & 1023;
          size_t idx = (size_t)((bb * 8 + h) * 1024 + l) * 64 + dh;
          if (part == 0) {
            oq[idx] = f2b(val * QSCALE);
          } else if (part == 1) {
            ok[idx] = f2b(val);
          } else {
            union { _Float16 h; unsigned short u; } cv;
            cv.h = (_Float16)val;
            ov[idx] = cv.u;
          }
        } else if (mode == 1) {
          int h = n >> 6, dh = n & 63;
          outf[(size_t)(h * 1024 + m) * 64 + dh] = val;
        } else {
          outf[(size_t)m * 512 + n] = val;
        }
      }
    }
  }
}

// ---------------- prep2: fold (K'=k+pos, bias) + V transpose-permute (one dispatch) ----------------
__global__ __launch_bounds__(256) void prep2(unsigned short* __restrict__ kbuf,
                                             const float* __restrict__ pos,
                                             const float* __restrict__ ub,
                                             const float* __restrict__ vbb,
                                             float* __restrict__ biasout,
                                             const unsigned short* __restrict__ v,
                                             unsigned short* __restrict__ vt) {
  int b = blockIdx.x;
  int t = threadIdx.x;
  if (b < 16384) {
    int wave = t >> 6, lane = t & 63;
    int g = b * 4 + wave;  // [0, B*H*L)
    int h = (g >> 10) & 7;
    int m = g & 1023;
    float kv = b2f(kbuf[(size_t)g * 64 + lane]);
    float pv = pos[(size_t)(h * 1024 + m) * 64 + lane];
    float val = ub[h * 64 + lane] * kv + vbb[h * 64 + lane] * pv;
#pragma unroll
    for (int off = 32; off > 0; off >>= 1) val += __shfl_down(val, off);
    if (lane == 0) biasout[g] = val * QSCALE;
    kbuf[(size_t)g * 64 + lane] = f2b(kv + pv);
  } else {
    // V fp16 (b,h,l,d) -> V2 fp16 (b,h,d,perm(l)); perm: dst = ((l>>2)&3)*16 + ((l>>4)&3)*4 + (l&3)
    __shared__ unsigned short Ts[64 * 68];
    int bb = b - 16384;
    int bh = bb >> 4, lt = bb & 15;
    const unsigned short* vg = v + (size_t)bh * 65536 + lt * 4096;
#pragma unroll
    for (int s = 0; s < 4; ++s) {
      int idx = t + s * 256;
      int r = idx >> 4, c4 = (idx & 15) << 2;
      *(ushort4*)&Ts[r * 68 + c4] = *(const ushort4*)(vg + r * 64 + c4);
    }
    __syncthreads();
#pragma unroll
    for (int s = 0; s < 4; ++s) {
      int idx = t + s * 256;
      int d = idx >> 4, l4 = (idx & 15) << 2;
      ushort4 o;
      o.x = Ts[(l4 + 0) * 68 + d];
      o.y = Ts[(l4 + 1) * 68 + d];
      o.z = Ts[(l4 + 2) * 68 + d];
      o.w = Ts[(l4 + 3) * 68 + d];
      int pb = ((l4 >> 2) & 3) * 16 + ((l4 >> 4) & 3) * 4;  // l4&3 == 0
      *(ushort4*)(vt + (size_t)bh * 65536 + d * 1024 + lt * 64 + pb) = o;
    }
  }
}

// ---------------- Flash attention: S^T = K'.Q^T (bf16 x32), O^T = V^T.P^T (fp16 x16) ----------------
// LDS-staged K'/V via global_load_lds with XOR-granule swizzle; bias staged once.
// grid (16, 64), 4 waves; wave w owns queries [16w, 16w+16).
__global__ __launch_bounds__(256) void flash_mfma(const unsigned short* __restrict__ qbf,
                                                  const unsigned short* __restrict__ kbf,
                                                  const unsigned short* __restrict__ vt,
                                                  const float* __restrict__ bias,
                                                  unsigned short* __restrict__ attn_out) {
  __shared__ alignas(16) unsigned short Ks[64 * 64];  // rows=key, swizzled granules over d
  __shared__ alignas(16) unsigned short Vs[64 * 64];  // rows=d, swizzled granules over perm(key)
  __shared__ alignas(16) float Bls[1024];
  const int t = threadIdx.x;
  const int lane = t & 63, w = t >> 6;
  const int c = lane & 15, q8 = lane >> 4;
  const int cc7 = c & 7;
  const int bh = blockIdx.y, qt = blockIdx.x;
  const unsigned short* qg = qbf + (size_t)bh * 65536;
  const unsigned short* kg = kbf + (size_t)bh * 65536;
  const unsigned short* vg = vt + (size_t)bh * 65536;
  const float* bg = bias + (size_t)bh * 1024;

  // stage bias once (4 KB, 1 inst/wave)
  GLDS16(bg + w * 256 + lane * 4, Bls + w * 256 + lane * 4);

  const int ql = qt * 64 + w * 16 + c;
  const bf16x8 bq0 = *(const bf16x8*)(qg + (size_t)ql * 64 + q8 * 8);
  const bf16x8 bq1 = *(const bf16x8*)(qg + (size_t)ql * 64 + 32 + q8 * 8);

  float m_st = -INFINITY, l_st = 0.0f;
  f32x4 o[4];
#pragma unroll
  for (int i = 0; i < 4; ++i) o[i] = (f32x4){0.f, 0.f, 0.f, 0.f};

  // staging geometry: lane covers rows r0, r0+8; granule slot = lane&7, source granule = slot^ (row&7)
  const int srow = lane >> 3;
  const int sgr = (lane & 7) ^ srow;
  const int r0 = w * 16 + srow;

  for (int kt = 0; kt < 16; ++kt) {
    __syncthreads();  // prior iteration's LDS reads done
#pragma unroll
    for (int j = 0; j < 2; ++j) {
      int r = r0 + j * 8;
      GLDS16(kg + (size_t)(kt * 64 + r) * 64 + sgr * 8, Ks + (r * 8 + (lane & 7)) * 8);
      GLDS16(vg + (size_t)r * 1024 + kt * 64 + sgr * 8, Vs + (r * 8 + (lane & 7)) * 8);
    }
    __syncthreads();  // DMA drained (vmcnt(0) before barrier)

    // S^T with bias as MFMA C-initializer
    f32x4 sc[4];
#pragma unroll
    for (int nt = 0; nt < 4; ++nt) {
      f32x4 ci = *(const f32x4*)&Bls[kt * 64 + nt * 16 + q8 * 4];
      const int row = nt * 16 + c;
      bf16x8 ak0 = *(const bf16x8*)&Ks[(row * 8 + (q8 ^ cc7)) * 8];
      bf16x8 ak1 = *(const bf16x8*)&Ks[(row * 8 + ((q8 + 4) ^ cc7)) * 8];
      ci = __builtin_amdgcn_mfma_f32_16x16x32_bf16(ak0, bq0, ci, 0, 0, 0);
      sc[nt] = __builtin_amdgcn_mfma_f32_16x16x32_bf16(ak1, bq1, ci, 0, 0, 0);
    }
    // online softmax (per-lane state for query c; reduce across q8 groups)
    float mx = sc[0][0];
#pragma unroll
    for (int nt = 0; nt < 4; ++nt)
#pragma unroll
      for (int r = 0; r < 4; ++r) mx = fmaxf(mx, sc[nt][r]);
    mx = fmaxf(mx, __shfl_xor(mx, 16));
    mx = fmaxf(mx, __shfl_xor(mx, 32));
    float mn = fmaxf(m_st, mx);
    float al = __builtin_amdgcn_exp2f(m_st - mn);
    float su = 0.0f;
    f16x4 pf[4];
#pragma unroll
    for (int nt = 0; nt < 4; ++nt)
#pragma unroll
      for (int r = 0; r < 4; ++r) {
        float p = __builtin_amdgcn_exp2f(sc[nt][r] - mn);
        su += p;
        pf[nt][r] = (_Float16)p;
      }
    su += __shfl_xor(su, 16);
    su += __shfl_xor(su, 32);
    l_st = l_st * al + su;
    m_st = mn;
#pragma unroll
    for (int i = 0; i < 4; ++i) o[i] *= al;
    // O^T += V^T . P^T  (x16 fp16; P straight from accumulators)
#pragma unroll
    for (int i = 0; i < 4; ++i) {
      const int row = i * 16 + c;
      f16x8 v01 = *(const f16x8*)&Vs[(row * 8 + ((2 * q8) ^ cc7)) * 8];
      f16x8 v23 = *(const f16x8*)&Vs[(row * 8 + ((2 * q8 + 1) ^ cc7)) * 8];
      f16x4 a0 = {v01[0], v01[1], v01[2], v01[3]};
      f16x4 a1 = {v01[4], v01[5], v01[6], v01[7]};
      f16x4 a2 = {v23[0], v23[1], v23[2], v23[3]};
      f16x4 a3 = {v23[4], v23[5], v23[6], v23[7]};
      o[i] = __builtin_amdgcn_mfma_f32_16x16x16f16(a0, pf[0], o[i], 0, 0, 0);
      o[i] = __builtin_amdgcn_mfma_f32_16x16x16f16(a1, pf[1], o[i], 0, 0, 0);
      o[i] = __builtin_amdgcn_mfma_f32_16x16x16f16(a2, pf[2], o[i], 0, 0, 0);
      o[i] = __builtin_amdgcn_mfma_f32_16x16x16f16(a3, pf[3], o[i], 0, 0, 0);
    }
  }
  // epilogue: lane holds O^T[d = 16i+4q8+r][query c]
  const int bidx = bh >> 3, h = bh & 7;
  float inv = 1.0f / l_st;
  size_t base = (size_t)(bidx * 1024 + ql) * 512 + h * 64;
#pragma unroll
  for (int i = 0; i < 4; ++i) {
    ushort4 ov4;
    ov4.x = f2b(o[i][0] * inv);
    ov4.y = f2b(o[i][1] * inv);
    ov4.z = f2b(o[i][2] * inv);
    ov4.w = f2b(o[i][3] * inv);
    *(ushort4*)(attn_out + base + i * 16 + q8 * 4) = ov4;
  }
}

extern "C" void kernel_launch(void* const* d_in, const int* in_sizes, int n_in,
                              void* d_out, int out_size, void* d_ws, size_t ws_size,
                              hipStream_t stream) {
  const float* x      = (const float*)d_in[0];
  const float* gamma  = (const float*)d_in[1];
  const float* beta   = (const float*)d_in[2];
  const float* w_qkv  = (const float*)d_in[3];
  const float* b_qkv  = (const float*)d_in[4];
  const float* w_pos  = (const float*)d_in[5];
  const float* w_out  = (const float*)d_in[6];
  const float* b_out  = (const float*)d_in[7];
  const float* u_bias = (const float*)d_in[8];
  const float* v_bias = (const float*)d_in[9];
  float* out = (float*)d_out;

  unsigned short* wsu = (unsigned short*)d_ws;
  unsigned short* xnb   = wsu;                    // 4M ushort
  unsigned short* peb   = wsu + 4194304;          // 512K
  unsigned short* wqkvb = wsu + 4718592;          // 768K
  unsigned short* wposb = wsu + 5505024;          // 256K
  unsigned short* woutb = wsu + 5767168;          // 256K
  unsigned short* qbf   = wsu + 6291456;          // 4M (bf16, pre-scaled)
  unsigned short* kbf   = wsu + 10485760;         // 4M (K' bf16 after fold)
  unsigned short* vbf   = wsu + 14680064;         // 4M (fp16)
  unsigned short* vtb   = wsu + 18874368;         // 4M (fp16, permuted-transposed)
  unsigned short* attnb = wsu + 23068672;         // 4M (bf16)
  float* posb  = (float*)(wsu + 27262976);        // 512K floats
  float* biasb = (float*)(wsu + 28311552);        // 64K floats (pre-scaled)

  prep1<<<11520, 256, 0, stream>>>(x, gamma, beta, xnb, peb,
                                   w_qkv, wqkvb, w_pos, wposb, w_out, woutb);
  // QKV GEMM (by<64) + pos GEMM (by>=64, bx<4) fused in one dispatch
  gemm_mfma<<<dim3(12, 72), 256, 0, stream>>>(xnb, wqkvb, b_qkv, nullptr, qbf, kbf, vbf,
                                              peb, wposb, posb, 512, 0);
  prep2<<<17408, 256, 0, stream>>>(kbf, posb, u_bias, v_bias, biasb, vbf, vtb);
  flash_mfma<<<dim3(16, 64), 256, 0, stream>>>(qbf, kbf, vtb, biasb, attnb);
  gemm_mfma<<<dim3(4, 64), 256, 0, stream>>>(attnb, woutb, b_out, out, nullptr, nullptr, nullptr,
                                             nullptr, nullptr, nullptr, 512, 2);
}

// Round 6
// 210.091 us; speedup vs baseline: 1.5351x; 1.0028x over previous
//
#include <hip/hip_runtime.h>
#include <math.h>

static constexpr int Bn = 8, Ln = 1024, Dm = 512, Hn = 8, DhN = 64;

typedef short bf16x8 __attribute__((ext_vector_type(8)));
typedef float f32x4 __attribute__((ext_vector_type(4)));
typedef _Float16 f16x4 __attribute__((ext_vector_type(4)));
typedef _Float16 f16x8 __attribute__((ext_vector_type(8)));
typedef unsigned int u32x4 __attribute__((ext_vector_type(4)));

// 0.125 * log2(e): folds the 1/sqrt(dh) scale AND the exp->exp2 conversion
#define QSCALE 0.1803368801111137f

static __device__ __forceinline__ unsigned short f2b(float f) {
  union { float f; unsigned int u; } x;
  x.f = f;
  unsigned int u = x.u;
  unsigned int r = (u + 0x7FFFu + ((u >> 16) & 1u)) >> 16;  // RNE
  return (unsigned short)r;
}
static __device__ __forceinline__ float b2f(unsigned short u) {
  union { unsigned int u; float f; } x;
  x.u = ((unsigned int)u) << 16;
  return x.f;
}

#define GLDS16(g, l)                                                        \
  __builtin_amdgcn_global_load_lds((const __attribute__((address_space(1))) void*)(g), \
                                   (__attribute__((address_space(3))) void*)(l), 16, 0, 0)

// ---------------- prep1: LayerNorm + PE + weight conversions (one dispatch) ----------------
__global__ __launch_bounds__(256) void prep1(const float* __restrict__ x,
                                             const float* __restrict__ gamma,
                                             const float* __restrict__ beta,
                                             unsigned short* __restrict__ xn,
                                             unsigned short* __restrict__ pe,
                                             const float* __restrict__ wq, unsigned short* __restrict__ wqb,
                                             const float* __restrict__ wp, unsigned short* __restrict__ wpb,
                                             const float* __restrict__ wo, unsigned short* __restrict__ wob) {
  int b = blockIdx.x;
  int t = threadIdx.x;
  if (b < 8192) {
    // LayerNorm row b
    const float2 v = *(const float2*)(x + (size_t)b * Dm + t * 2);
    float s = v.x + v.y;
    float sq = v.x * v.x + v.y * v.y;
#pragma unroll
    for (int off = 32; off > 0; off >>= 1) {
      s += __shfl_down(s, off);
      sq += __shfl_down(sq, off);
    }
    __shared__ float red[8];
    int wave = t >> 6, lane = t & 63;
    if (lane == 0) { red[wave * 2] = s; red[wave * 2 + 1] = sq; }
    __syncthreads();
    float S = red[0] + red[2] + red[4] + red[6];
    float SQ = red[1] + red[3] + red[5] + red[7];
    float mu = S * (1.0f / Dm);
    float var = SQ * (1.0f / Dm) - mu * mu;
    float rstd = rsqrtf(var + 1e-5f);
    int c = t * 2;
    ushort2 o;
    o.x = f2b((v.x - mu) * rstd * gamma[c] + beta[c]);
    o.y = f2b((v.y - mu) * rstd * gamma[c + 1] + beta[c + 1]);
    *(ushort2*)(xn + (size_t)b * Dm + c) = o;
  } else if (b < 10240) {
    int idx = (b - 8192) * 256 + t;
    int l = idx >> 9, k = idx & 511;
    float freq = expf(-0.0359778921f * (float)k);
    float angle = (float)(l - k) * freq;
    pe[idx] = f2b((k & 1) ? sinf(angle) : cosf(angle));
  } else {
    int cb = b - 10240;  // 0..1279
    const float* src;
    unsigned short* dst;
    int off;
    if (cb < 768) { src = wq; dst = wqb; off = cb; }
    else if (cb < 1024) { src = wp; dst = wpb; off = cb - 768; }
    else { src = wo; dst = wob; off = cb - 1024; }
    int i = off * 256 + t;
    float4 v = *(const float4*)(src + (size_t)i * 4);
    ushort4 o;
    o.x = f2b(v.x); o.y = f2b(v.y); o.z = f2b(v.z); o.w = f2b(v.w);
    *(ushort4*)(dst + (size_t)i * 4) = o;
  }
}

// ---------------- bf16 MFMA NT GEMM with VGPR-prefetch double-buffering ----------------
// Blocks with blockIdx.y >= 64 run the small pos GEMM (A2/B2 -> outf2, mode 1).
// mode 0: scatter q (bf16, pre-scaled) / k (bf16) / v (fp16) in (B,H,L,Dh)
// mode 1: posb f32 (H,L,Dh); mode 2: outf f32 row-major (N=512).
__global__ __launch_bounds__(256) void gemm_mfma(const unsigned short* __restrict__ Ain,
                                                 const unsigned short* __restrict__ Bwin,
                                                 const float* __restrict__ biasin,
                                                 float* __restrict__ outfin,
                                                 unsigned short* __restrict__ oq,
                                                 unsigned short* __restrict__ ok,
                                                 unsigned short* __restrict__ ov,
                                                 const unsigned short* __restrict__ A2,
                                                 const unsigned short* __restrict__ B2,
                                                 float* __restrict__ outf2,
                                                 int K, int mode) {
  int by = blockIdx.y, bx = blockIdx.x;
  const unsigned short* A = Ain;
  const unsigned short* Bw = Bwin;
  const float* bias = biasin;
  float* outf = outfin;
  if (by >= 64) {
    if (bx >= 4) return;
    A = A2; Bw = B2; bias = nullptr; outf = outf2; mode = 1; by -= 64;
  }
  __shared__ alignas(16) unsigned short As[128 * 64];
  __shared__ alignas(16) unsigned short Bs[128 * 64];
  const int t = threadIdx.x;
  const int lane = t & 63, w = t >> 6;
  const int c = lane & 15, q8 = lane >> 4;
  const int wm = (w & 1) * 64, wn = (w >> 1) * 64;
  const int m0 = by * 128, n0 = bx * 128;

  f32x4 acc[4][4];
#pragma unroll
  for (int i = 0; i < 4; ++i)
#pragma unroll
    for (int j = 0; j < 4; ++j) acc[i][j] = (f32x4){0.f, 0.f, 0.f, 0.f};

  // staging geometry: granule g = (w*4+j)*64 + lane holds (row=g>>3, colgran=(g&7)^(row&7))
  const int srow = lane >> 3;
  const int scol = ((lane & 7) ^ srow) * 8;
  int arow[4];
#pragma unroll
  for (int j = 0; j < 4; ++j) arow[j] = w * 32 + j * 8 + srow;

  // prefetch tile 0 into VGPRs
  u32x4 pa[4], pb[4];
#pragma unroll
  for (int j = 0; j < 4; ++j) {
    pa[j] = *(const u32x4*)(A + (size_t)(m0 + arow[j]) * K + scol);
    pb[j] = *(const u32x4*)(Bw + (size_t)(n0 + arow[j]) * K + scol);
  }

  for (int k0 = 0; k0 < K; k0 += 64) {
    __syncthreads();  // prior compute finished reading LDS
#pragma unroll
    for (int j = 0; j < 4; ++j) {
      *(u32x4*)&As[((w * 4 + j) * 64 + lane) * 8] = pa[j];
      *(u32x4*)&Bs[((w * 4 + j) * 64 + lane) * 8] = pb[j];
    }
    __syncthreads();
    // prefetch next tile (latency overlaps the compute below)
    if (k0 + 64 < K) {
#pragma unroll
      for (int j = 0; j < 4; ++j) {
        pa[j] = *(const u32x4*)(A + (size_t)(m0 + arow[j]) * K + k0 + 64 + scol);
        pb[j] = *(const u32x4*)(Bw + (size_t)(n0 + arow[j]) * K + k0 + 64 + scol);
      }
    }
#pragma unroll
    for (int kk = 0; kk < 2; ++kk) {
      bf16x8 a[4], b[4];
      const int q = kk * 4 + q8;
#pragma unroll
      for (int i = 0; i < 4; ++i) {
        int r = wm + i * 16 + c;
        a[i] = *(const bf16x8*)&As[r * 64 + ((q ^ (r & 7)) * 8)];
      }
#pragma unroll
      for (int j = 0; j < 4; ++j) {
        int r = wn + j * 16 + c;
        b[j] = *(const bf16x8*)&Bs[r * 64 + ((q ^ (r & 7)) * 8)];
      }
#pragma unroll
      for (int i = 0; i < 4; ++i)
#pragma unroll
        for (int j = 0; j < 4; ++j)
          acc[i][j] = __builtin_amdgcn_mfma_f32_16x16x32_bf16(a[i], b[j], acc[i][j], 0, 0, 0);
    }
  }
#pragma unroll
  for (int i = 0; i < 4; ++i) {
#pragma unroll
    for (int r = 0; r < 4; ++r) {
      int m = m0 + wm + i * 16 + q8 * 4 + r;
#pragma unroll
      for (int j = 0; j < 4; ++j) {
        int n = n0 + wn + j * 16 + c;
        float val = acc[i][j][r] + (bias ? bias[n] : 0.0f);
        if (mode == 0) {
          int part = n >> 9, h = (n >> 6) & 7, dh = n & 63;
          int bb = m >> 10, l = m & 1023;
          size_t idx = (size_t)((bb * 8 + h) * 1024 + l) * 64 + dh;
          if (part == 0) {
            oq[idx] = f2b(val * QSCALE);
          } else if (part == 1) {
            ok[idx] = f2b(val);
          } else {
            union { _Float16 h; unsigned short u; } cv;
            cv.h = (_Float16)val;
            ov[idx] = cv.u;
          }
        } else if (mode == 1) {
          int h = n >> 6, dh = n & 63;
          outf[(size_t)(h * 1024 + m) * 64 + dh] = val;
        } else {
          outf[(size_t)m * 512 + n] = val;
        }
      }
    }
  }
}

// ---------------- prep2: fold (K'=k+pos, bias) + V transpose-permute (one dispatch) ----------------
__global__ __launch_bounds__(256) void prep2(unsigned short* __restrict__ kbuf,
                                             const float* __restrict__ pos,
                                             const float* __restrict__ ub,
                                             const float* __restrict__ vbb,
                                             float* __restrict__ biasout,
                                             const unsigned short* __restrict__ v,
                                             unsigned short* __restrict__ vt) {
  int b = blockIdx.x;
  int t = threadIdx.x;
  if (b < 16384) {
    int wave = t >> 6, lane = t & 63;
    int g = b * 4 + wave;  // [0, B*H*L)
    int h = (g >> 10) & 7;
    int m = g & 1023;
    float kv = b2f(kbuf[(size_t)g * 64 + lane]);
    float pv = pos[(size_t)(h * 1024 + m) * 64 + lane];
    float val = ub[h * 64 + lane] * kv + vbb[h * 64 + lane] * pv;
#pragma unroll
    for (int off = 32; off > 0; off >>= 1) val += __shfl_down(val, off);
    if (lane == 0) biasout[g] = val * QSCALE;
    kbuf[(size_t)g * 64 + lane] = f2b(kv + pv);
  } else {
    // V fp16 (b,h,l,d) -> V2 fp16 (b,h,d,perm(l)); perm: dst = ((l>>2)&3)*16 + ((l>>4)&3)*4 + (l&3)
    __shared__ unsigned short Ts[64 * 68];
    int bb = b - 16384;
    int bh = bb >> 4, lt = bb & 15;
    const unsigned short* vg = v + (size_t)bh * 65536 + lt * 4096;
#pragma unroll
    for (int s = 0; s < 4; ++s) {
      int idx = t + s * 256;
      int r = idx >> 4, c4 = (idx & 15) << 2;
      *(ushort4*)&Ts[r * 68 + c4] = *(const ushort4*)(vg + r * 64 + c4);
    }
    __syncthreads();
#pragma unroll
    for (int s = 0; s < 4; ++s) {
      int idx = t + s * 256;
      int d = idx >> 4, l4 = (idx & 15) << 2;
      ushort4 o;
      o.x = Ts[(l4 + 0) * 68 + d];
      o.y = Ts[(l4 + 1) * 68 + d];
      o.z = Ts[(l4 + 2) * 68 + d];
      o.w = Ts[(l4 + 3) * 68 + d];
      int pb = ((l4 >> 2) & 3) * 16 + ((l4 >> 4) & 3) * 4;  // l4&3 == 0
      *(ushort4*)(vt + (size_t)bh * 65536 + d * 1024 + lt * 64 + pb) = o;
    }
  }
}

// ---------------- Flash attention: S^T = K'.Q^T (bf16 x32), O^T = V^T.P^T (fp16 x16) ----------------
// LDS-staged K'/V with VGPR-prefetch double-buffering; bias staged once via DMA.
// grid (16, 64), 4 waves; wave w owns queries [16w, 16w+16).
__global__ __launch_bounds__(256) void flash_mfma(const unsigned short* __restrict__ qbf,
                                                  const unsigned short* __restrict__ kbf,
                                                  const unsigned short* __restrict__ vt,
                                                  const float* __restrict__ bias,
                                                  unsigned short* __restrict__ attn_out) {
  __shared__ alignas(16) unsigned short Ks[64 * 64];  // rows=key, swizzled granules over d
  __shared__ alignas(16) unsigned short Vs[64 * 64];  // rows=d, swizzled granules over perm(key)
  __shared__ alignas(16) float Bls[1024];
  const int t = threadIdx.x;
  const int lane = t & 63, w = t >> 6;
  const int c = lane & 15, q8 = lane >> 4;
  const int cc7 = c & 7;
  const int bh = blockIdx.y, qt = blockIdx.x;
  const unsigned short* qg = qbf + (size_t)bh * 65536;
  const unsigned short* kg = kbf + (size_t)bh * 65536;
  const unsigned short* vg = vt + (size_t)bh * 65536;
  const float* bg = bias + (size_t)bh * 1024;

  // stage bias once (4 KB, 1 inst/wave)
  GLDS16(bg + w * 256 + lane * 4, Bls + w * 256 + lane * 4);

  const int ql = qt * 64 + w * 16 + c;
  const bf16x8 bq0 = *(const bf16x8*)(qg + (size_t)ql * 64 + q8 * 8);
  const bf16x8 bq1 = *(const bf16x8*)(qg + (size_t)ql * 64 + 32 + q8 * 8);

  float m_st = -INFINITY, l_st = 0.0f;
  f32x4 o[4];
#pragma unroll
  for (int i = 0; i < 4; ++i) o[i] = (f32x4){0.f, 0.f, 0.f, 0.f};

  // staging geometry: lane covers rows r0, r0+8; granule slot = lane&7, source granule = slot^(row&7)
  const int srow = lane >> 3;
  const int sgr = (lane & 7) ^ srow;
  const int r0 = w * 16 + srow;

  // prefetch kt=0 into VGPRs
  u32x4 pk[2], pv[2];
#pragma unroll
  for (int j = 0; j < 2; ++j) {
    int r = r0 + j * 8;
    pk[j] = *(const u32x4*)(kg + (size_t)r * 64 + sgr * 8);
    pv[j] = *(const u32x4*)(vg + (size_t)r * 1024 + sgr * 8);
  }

  for (int kt = 0; kt < 16; ++kt) {
    __syncthreads();  // prior iteration's LDS reads done
#pragma unroll
    for (int j = 0; j < 2; ++j) {
      int r = r0 + j * 8;
      *(u32x4*)&Ks[(r * 8 + (lane & 7)) * 8] = pk[j];
      *(u32x4*)&Vs[(r * 8 + (lane & 7)) * 8] = pv[j];
    }
    __syncthreads();
    // prefetch next kt (latency overlaps compute below)
    if (kt < 15) {
#pragma unroll
      for (int j = 0; j < 2; ++j) {
        int r = r0 + j * 8;
        pk[j] = *(const u32x4*)(kg + (size_t)((kt + 1) * 64 + r) * 64 + sgr * 8);
        pv[j] = *(const u32x4*)(vg + (size_t)r * 1024 + (kt + 1) * 64 + sgr * 8);
      }
    }

    // S^T with bias as MFMA C-initializer
    f32x4 sc[4];
#pragma unroll
    for (int nt = 0; nt < 4; ++nt) {
      f32x4 ci = *(const f32x4*)&Bls[kt * 64 + nt * 16 + q8 * 4];
      const int row = nt * 16 + c;
      bf16x8 ak0 = *(const bf16x8*)&Ks[(row * 8 + (q8 ^ cc7)) * 8];
      bf16x8 ak1 = *(const bf16x8*)&Ks[(row * 8 + ((q8 + 4) ^ cc7)) * 8];
      ci = __builtin_amdgcn_mfma_f32_16x16x32_bf16(ak0, bq0, ci, 0, 0, 0);
      sc[nt] = __builtin_amdgcn_mfma_f32_16x16x32_bf16(ak1, bq1, ci, 0, 0, 0);
    }
    // online softmax (per-lane state for query c; reduce across q8 groups)
    float mx = sc[0][0];
#pragma unroll
    for (int nt = 0; nt < 4; ++nt)
#pragma unroll
      for (int r = 0; r < 4; ++r) mx = fmaxf(mx, sc[nt][r]);
    mx = fmaxf(mx, __shfl_xor(mx, 16));
    mx = fmaxf(mx, __shfl_xor(mx, 32));
    float mn = fmaxf(m_st, mx);
    float al = __builtin_amdgcn_exp2f(m_st - mn);
    float su = 0.0f;
    f16x4 pf[4];
#pragma unroll
    for (int nt = 0; nt < 4; ++nt)
#pragma unroll
      for (int r = 0; r < 4; ++r) {
        float p = __builtin_amdgcn_exp2f(sc[nt][r] - mn);
        su += p;
        pf[nt][r] = (_Float16)p;
      }
    su += __shfl_xor(su, 16);
    su += __shfl_xor(su, 32);
    l_st = l_st * al + su;
    m_st = mn;
#pragma unroll
    for (int i = 0; i < 4; ++i) o[i] *= al;
    // O^T += V^T . P^T  (x16 fp16; P straight from accumulators)
#pragma unroll
    for (int i = 0; i < 4; ++i) {
      const int row = i * 16 + c;
      f16x8 v01 = *(const f16x8*)&Vs[(row * 8 + ((2 * q8) ^ cc7)) * 8];
      f16x8 v23 = *(const f16x8*)&Vs[(row * 8 + ((2 * q8 + 1) ^ cc7)) * 8];
      f16x4 a0 = {v01[0], v01[1], v01[2], v01[3]};
      f16x4 a1 = {v01[4], v01[5], v01[6], v01[7]};
      f16x4 a2 = {v23[0], v23[1], v23[2], v23[3]};
      f16x4 a3 = {v23[4], v23[5], v23[6], v23[7]};
      o[i] = __builtin_amdgcn_mfma_f32_16x16x16f16(a0, pf[0], o[i], 0, 0, 0);
      o[i] = __builtin_amdgcn_mfma_f32_16x16x16f16(a1, pf[1], o[i], 0, 0, 0);
      o[i] = __builtin_amdgcn_mfma_f32_16x16x16f16(a2, pf[2], o[i], 0, 0, 0);
      o[i] = __builtin_amdgcn_mfma_f32_16x16x16f16(a3, pf[3], o[i], 0, 0, 0);
    }
  }
  // epilogue: lane holds O^T[d = 16i+4q8+r][query c]
  const int bidx = bh >> 3, h = bh & 7;
  float inv = 1.0f / l_st;
  size_t base = (size_t)(bidx * 1024 + ql) * 512 + h * 64;
#pragma unroll
  for (int i = 0; i < 4; ++i) {
    ushort4 ov4;
    ov4.x = f2b(o[i][0] * inv);
    ov4.y = f2b(o[i][1] * inv);
    ov4.z = f2b(o[i][2] * inv);
    ov4.w = f2b(o[i][3] * inv);
    *(ushort4*)(attn_out + base + i * 16 + q8 * 4) = ov4;
  }
}

extern "C" void kernel_launch(void* const* d_in, const int* in_sizes, int n_in,
                              void* d_out, int out_size, void* d_ws, size_t ws_size,
                              hipStream_t stream) {
  const float* x      = (const float*)d_in[0];
  const float* gamma  = (const float*)d_in[1];
  const float* beta   = (const float*)d_in[2];
  const float* w_qkv  = (const float*)d_in[3];
  const float* b_qkv  = (const float*)d_in[4];
  const float* w_pos  = (const float*)d_in[5];
  const float* w_out  = (const float*)d_in[6];
  const float* b_out  = (const float*)d_in[7];
  const float* u_bias = (const float*)d_in[8];
  const float* v_bias = (const float*)d_in[9];
  float* out = (float*)d_out;

  unsigned short* wsu = (unsigned short*)d_ws;
  unsigned short* xnb   = wsu;                    // 4M ushort
  unsigned short* peb   = wsu + 4194304;          // 512K
  unsigned short* wqkvb = wsu + 4718592;          // 768K
  unsigned short* wposb = wsu + 5505024;          // 256K
  unsigned short* woutb = wsu + 5767168;          // 256K
  unsigned short* qbf   = wsu + 6291456;          // 4M (bf16, pre-scaled)
  unsigned short* kbf   = wsu + 10485760;         // 4M (K' bf16 after fold)
  unsigned short* vbf   = wsu + 14680064;         // 4M (fp16)
  unsigned short* vtb   = wsu + 18874368;         // 4M (fp16, permuted-transposed)
  unsigned short* attnb = wsu + 23068672;         // 4M (bf16)
  float* posb  = (float*)(wsu + 27262976);        // 512K floats
  float* biasb = (float*)(wsu + 28311552);        // 64K floats (pre-scaled)

  prep1<<<11520, 256, 0, stream>>>(x, gamma, beta, xnb, peb,
                                   w_qkv, wqkvb, w_pos, wposb, w_out, woutb);
  // QKV GEMM (by<64) + pos GEMM (by>=64, bx<4) fused in one dispatch
  gemm_mfma<<<dim3(12, 72), 256, 0, stream>>>(xnb, wqkvb, b_qkv, nullptr, qbf, kbf, vbf,
                                              peb, wposb, posb, 512, 0);
  prep2<<<17408, 256, 0, stream>>>(kbf, posb, u_bias, v_bias, biasb, vbf, vtb);
  flash_mfma<<<dim3(16, 64), 256, 0, stream>>>(qbf, kbf, vtb, biasb, attnb);
  gemm_mfma<<<dim3(4, 64), 256, 0, stream>>>(attnb, woutb, b_out, out, nullptr, nullptr, nullptr,
                                             nullptr, nullptr, nullptr, 512, 2);
}

// Round 7
// 187.839 us; speedup vs baseline: 1.7169x; 1.1185x over previous
//
#include <hip/hip_runtime.h>
#include <math.h>

static constexpr int Bn = 8, Ln = 1024, Dm = 512, Hn = 8, DhN = 64;

typedef short bf16x8 __attribute__((ext_vector_type(8)));
typedef float f32x4 __attribute__((ext_vector_type(4)));
typedef _Float16 f16x4 __attribute__((ext_vector_type(4)));
typedef _Float16 f16x8 __attribute__((ext_vector_type(8)));
typedef unsigned int u32x4 __attribute__((ext_vector_type(4)));

// 0.125 * log2(e): folds the 1/sqrt(dh) scale AND the exp->exp2 conversion
#define QSCALE 0.1803368801111137f

static __device__ __forceinline__ unsigned short f2b(float f) {
  union { float f; unsigned int u; } x;
  x.f = f;
  unsigned int u = x.u;
  unsigned int r = (u + 0x7FFFu + ((u >> 16) & 1u)) >> 16;  // RNE
  return (unsigned short)r;
}
static __device__ __forceinline__ float b2f(unsigned short u) {
  union { unsigned int u; float f; } x;
  x.u = ((unsigned int)u) << 16;
  return x.f;
}

#define GLDS16(g, l)                                                        \
  __builtin_amdgcn_global_load_lds((const __attribute__((address_space(1))) void*)(g), \
                                   (__attribute__((address_space(3))) void*)(l), 16, 0, 0)

// ---------------- prep1: LayerNorm + PE + weight conversions (one dispatch) ----------------
__global__ __launch_bounds__(256) void prep1(const float* __restrict__ x,
                                             const float* __restrict__ gamma,
                                             const float* __restrict__ beta,
                                             unsigned short* __restrict__ xn,
                                             unsigned short* __restrict__ pe,
                                             const float* __restrict__ wq, unsigned short* __restrict__ wqb,
                                             const float* __restrict__ wp, unsigned short* __restrict__ wpb,
                                             const float* __restrict__ wo, unsigned short* __restrict__ wob) {
  int b = blockIdx.x;
  int t = threadIdx.x;
  if (b < 8192) {
    // LayerNorm row b
    const float2 v = *(const float2*)(x + (size_t)b * Dm + t * 2);
    float s = v.x + v.y;
    float sq = v.x * v.x + v.y * v.y;
#pragma unroll
    for (int off = 32; off > 0; off >>= 1) {
      s += __shfl_down(s, off);
      sq += __shfl_down(sq, off);
    }
    __shared__ float red[8];
    int wave = t >> 6, lane = t & 63;
    if (lane == 0) { red[wave * 2] = s; red[wave * 2 + 1] = sq; }
    __syncthreads();
    float S = red[0] + red[2] + red[4] + red[6];
    float SQ = red[1] + red[3] + red[5] + red[7];
    float mu = S * (1.0f / Dm);
    float var = SQ * (1.0f / Dm) - mu * mu;
    float rstd = rsqrtf(var + 1e-5f);
    int c = t * 2;
    ushort2 o;
    o.x = f2b((v.x - mu) * rstd * gamma[c] + beta[c]);
    o.y = f2b((v.y - mu) * rstd * gamma[c + 1] + beta[c + 1]);
    *(ushort2*)(xn + (size_t)b * Dm + c) = o;
  } else if (b < 10240) {
    int idx = (b - 8192) * 256 + t;
    int l = idx >> 9, k = idx & 511;
    float freq = expf(-0.0359778921f * (float)k);
    float angle = (float)(l - k) * freq;
    pe[idx] = f2b((k & 1) ? sinf(angle) : cosf(angle));
  } else {
    int cb = b - 10240;  // 0..1279
    const float* src;
    unsigned short* dst;
    int off;
    if (cb < 768) { src = wq; dst = wqb; off = cb; }
    else if (cb < 1024) { src = wp; dst = wpb; off = cb - 768; }
    else { src = wo; dst = wob; off = cb - 1024; }
    int i = off * 256 + t;
    float4 v = *(const float4*)(src + (size_t)i * 4);
    ushort4 o;
    o.x = f2b(v.x); o.y = f2b(v.y); o.z = f2b(v.z); o.w = f2b(v.w);
    *(ushort4*)(dst + (size_t)i * 4) = o;
  }
}

// ---------------- bf16 MFMA NT GEMM: 64x64 tile, DMA staging, high-TLP ----------------
// Blocks with blockIdx.y >= 128 run the small pos GEMM (A2/B2 -> outf2, mode 1, bx<8).
// mode 0: scatter q (bf16, pre-scaled) / k (bf16) / v (fp16) in (B,H,L,Dh)
// mode 1: posb f32 (H,L,Dh); mode 2: outf f32 row-major (N=512).
__global__ __launch_bounds__(256, 8) void gemm_mfma(const unsigned short* __restrict__ Ain,
                                                    const unsigned short* __restrict__ Bwin,
                                                    const float* __restrict__ biasin,
                                                    float* __restrict__ outfin,
                                                    unsigned short* __restrict__ oq,
                                                    unsigned short* __restrict__ ok,
                                                    unsigned short* __restrict__ ov,
                                                    const unsigned short* __restrict__ A2,
                                                    const unsigned short* __restrict__ B2,
                                                    float* __restrict__ outf2,
                                                    int K, int mode) {
  int by = blockIdx.y, bx = blockIdx.x;
  const unsigned short* A = Ain;
  const unsigned short* Bw = Bwin;
  const float* bias = biasin;
  float* outf = outfin;
  if (by >= 128) {
    if (bx >= 8) return;
    A = A2; Bw = B2; bias = nullptr; outf = outf2; mode = 1; by -= 128;
  }
  __shared__ alignas(16) unsigned short As[64 * 64];
  __shared__ alignas(16) unsigned short Bs[64 * 64];
  const int t = threadIdx.x;
  const int lane = t & 63, w = t >> 6;
  const int c = lane & 15, q8 = lane >> 4;
  const int wm = (w & 1) * 32, wn = (w >> 1) * 32;
  const int m0 = by * 64, n0 = bx * 64;

  f32x4 acc[2][2];
#pragma unroll
  for (int i = 0; i < 2; ++i)
#pragma unroll
    for (int j = 0; j < 2; ++j) acc[i][j] = (f32x4){0.f, 0.f, 0.f, 0.f};

  // staging geometry: granule g = j*256 + w*64 + lane -> row = g>>3, slot = lane&7,
  // stored source-granule = slot ^ (row&7);  row&7 == lane>>3 for every inst.
  const int srow = lane >> 3;
  const int sgr = (lane & 7) ^ srow;

  for (int k0 = 0; k0 < K; k0 += 64) {
    __syncthreads();
#pragma unroll
    for (int j = 0; j < 2; ++j) {
      int r = j * 32 + w * 8 + srow;
      GLDS16(A + (size_t)(m0 + r) * K + k0 + sgr * 8, As + (j * 256 + w * 64 + lane) * 8);
      GLDS16(Bw + (size_t)(n0 + r) * K + k0 + sgr * 8, Bs + (j * 256 + w * 64 + lane) * 8);
    }
    __syncthreads();
#pragma unroll
    for (int kk = 0; kk < 2; ++kk) {
      bf16x8 a[2], b[2];
      const int q = kk * 4 + q8;
#pragma unroll
      for (int i = 0; i < 2; ++i) {
        int r = wm + i * 16 + c;
        a[i] = *(const bf16x8*)&As[(r * 8 + (q ^ (r & 7))) * 8];
      }
#pragma unroll
      for (int j = 0; j < 2; ++j) {
        int r = wn + j * 16 + c;
        b[j] = *(const bf16x8*)&Bs[(r * 8 + (q ^ (r & 7))) * 8];
      }
#pragma unroll
      for (int i = 0; i < 2; ++i)
#pragma unroll
        for (int j = 0; j < 2; ++j)
          acc[i][j] = __builtin_amdgcn_mfma_f32_16x16x32_bf16(a[i], b[j], acc[i][j], 0, 0, 0);
    }
  }
#pragma unroll
  for (int i = 0; i < 2; ++i) {
#pragma unroll
    for (int r = 0; r < 4; ++r) {
      int m = m0 + wm + i * 16 + q8 * 4 + r;
#pragma unroll
      for (int j = 0; j < 2; ++j) {
        int n = n0 + wn + j * 16 + c;
        float val = acc[i][j][r] + (bias ? bias[n] : 0.0f);
        if (mode == 0) {
          int part = n >> 9, h = (n >> 6) & 7, dh = n & 63;
          int bb = m >> 10, l = m & 1023;
          size_t idx = (size_t)((bb * 8 + h) * 1024 + l) * 64 + dh;
          if (part == 0) {
            oq[idx] = f2b(val * QSCALE);
          } else if (part == 1) {
            ok[idx] = f2b(val);
          } else {
            union { _Float16 h; unsigned short u; } cv;
            cv.h = (_Float16)val;
            ov[idx] = cv.u;
          }
        } else if (mode == 1) {
          int h = n >> 6, dh = n & 63;
          outf[(size_t)(h * 1024 + m) * 64 + dh] = val;
        } else {
          outf[(size_t)m * 512 + n] = val;
        }
      }
    }
  }
}

// ---------------- prep2: fold (K'=k+pos, bias) + V transpose-permute (one dispatch) ----------------
__global__ __launch_bounds__(256) void prep2(unsigned short* __restrict__ kbuf,
                                             const float* __restrict__ pos,
                                             const float* __restrict__ ub,
                                             const float* __restrict__ vbb,
                                             float* __restrict__ biasout,
                                             const unsigned short* __restrict__ v,
                                             unsigned short* __restrict__ vt) {
  int b = blockIdx.x;
  int t = threadIdx.x;
  if (b < 16384) {
    int wave = t >> 6, lane = t & 63;
    int g = b * 4 + wave;  // [0, B*H*L)
    int h = (g >> 10) & 7;
    int m = g & 1023;
    float kv = b2f(kbuf[(size_t)g * 64 + lane]);
    float pv = pos[(size_t)(h * 1024 + m) * 64 + lane];
    float val = ub[h * 64 + lane] * kv + vbb[h * 64 + lane] * pv;
#pragma unroll
    for (int off = 32; off > 0; off >>= 1) val += __shfl_down(val, off);
    if (lane == 0) biasout[g] = val * QSCALE;
    kbuf[(size_t)g * 64 + lane] = f2b(kv + pv);
  } else {
    // V fp16 (b,h,l,d) -> V2 fp16 (b,h,d,perm(l)); perm: dst = ((l>>2)&3)*16 + ((l>>4)&3)*4 + (l&3)
    __shared__ unsigned short Ts[64 * 68];
    int bb = b - 16384;
    int bh = bb >> 4, lt = bb & 15;
    const unsigned short* vg = v + (size_t)bh * 65536 + lt * 4096;
#pragma unroll
    for (int s = 0; s < 4; ++s) {
      int idx = t + s * 256;
      int r = idx >> 4, c4 = (idx & 15) << 2;
      *(ushort4*)&Ts[r * 68 + c4] = *(const ushort4*)(vg + r * 64 + c4);
    }
    __syncthreads();
#pragma unroll
    for (int s = 0; s < 4; ++s) {
      int idx = t + s * 256;
      int d = idx >> 4, l4 = (idx & 15) << 2;
      ushort4 o;
      o.x = Ts[(l4 + 0) * 68 + d];
      o.y = Ts[(l4 + 1) * 68 + d];
      o.z = Ts[(l4 + 2) * 68 + d];
      o.w = Ts[(l4 + 3) * 68 + d];
      int pb = ((l4 >> 2) & 3) * 16 + ((l4 >> 4) & 3) * 4;  // l4&3 == 0
      *(ushort4*)(vt + (size_t)bh * 65536 + d * 1024 + lt * 64 + pb) = o;
    }
  }
}

// ---------------- Flash attention: S^T = K'.Q^T (bf16 x32), O^T = V^T.P^T (fp16 x16) ----------------
// LDS-staged K'/V with VGPR-prefetch double-buffering; bias staged once via DMA.
// grid (16, 64), 4 waves; wave w owns queries [16w, 16w+16).
__global__ __launch_bounds__(256) void flash_mfma(const unsigned short* __restrict__ qbf,
                                                  const unsigned short* __restrict__ kbf,
                                                  const unsigned short* __restrict__ vt,
                                                  const float* __restrict__ bias,
                                                  unsigned short* __restrict__ attn_out) {
  __shared__ alignas(16) unsigned short Ks[64 * 64];  // rows=key, swizzled granules over d
  __shared__ alignas(16) unsigned short Vs[64 * 64];  // rows=d, swizzled granules over perm(key)
  __shared__ alignas(16) float Bls[1024];
  const int t = threadIdx.x;
  const int lane = t & 63, w = t >> 6;
  const int c = lane & 15, q8 = lane >> 4;
  const int cc7 = c & 7;
  const int bh = blockIdx.y, qt = blockIdx.x;
  const unsigned short* qg = qbf + (size_t)bh * 65536;
  const unsigned short* kg = kbf + (size_t)bh * 65536;
  const unsigned short* vg = vt + (size_t)bh * 65536;
  const float* bg = bias + (size_t)bh * 1024;

  // stage bias once (4 KB, 1 inst/wave)
  GLDS16(bg + w * 256 + lane * 4, Bls + w * 256 + lane * 4);

  const int ql = qt * 64 + w * 16 + c;
  const bf16x8 bq0 = *(const bf16x8*)(qg + (size_t)ql * 64 + q8 * 8);
  const bf16x8 bq1 = *(const bf16x8*)(qg + (size_t)ql * 64 + 32 + q8 * 8);

  float m_st = -INFINITY, l_st = 0.0f;
  f32x4 o[4];
#pragma unroll
  for (int i = 0; i < 4; ++i) o[i] = (f32x4){0.f, 0.f, 0.f, 0.f};

  // staging geometry: lane covers rows r0, r0+8; granule slot = lane&7, source granule = slot^(row&7)
  const int srow = lane >> 3;
  const int sgr = (lane & 7) ^ srow;
  const int r0 = w * 16 + srow;

  // prefetch kt=0 into VGPRs
  u32x4 pk[2], pv[2];
#pragma unroll
  for (int j = 0; j < 2; ++j) {
    int r = r0 + j * 8;
    pk[j] = *(const u32x4*)(kg + (size_t)r * 64 + sgr * 8);
    pv[j] = *(const u32x4*)(vg + (size_t)r * 1024 + sgr * 8);
  }

  for (int kt = 0; kt < 16; ++kt) {
    __syncthreads();  // prior iteration's LDS reads done
#pragma unroll
    for (int j = 0; j < 2; ++j) {
      int r = r0 + j * 8;
      *(u32x4*)&Ks[(r * 8 + (lane & 7)) * 8] = pk[j];
      *(u32x4*)&Vs[(r * 8 + (lane & 7)) * 8] = pv[j];
    }
    __syncthreads();
    // prefetch next kt (latency overlaps compute below)
    if (kt < 15) {
#pragma unroll
      for (int j = 0; j < 2; ++j) {
        int r = r0 + j * 8;
        pk[j] = *(const u32x4*)(kg + (size_t)((kt + 1) * 64 + r) * 64 + sgr * 8);
        pv[j] = *(const u32x4*)(vg + (size_t)r * 1024 + (kt + 1) * 64 + sgr * 8);
      }
    }

    // S^T with bias as MFMA C-initializer
    f32x4 sc[4];
#pragma unroll
    for (int nt = 0; nt < 4; ++nt) {
      f32x4 ci = *(const f32x4*)&Bls[kt * 64 + nt * 16 + q8 * 4];
      const int row = nt * 16 + c;
      bf16x8 ak0 = *(const bf16x8*)&Ks[(row * 8 + (q8 ^ cc7)) * 8];
      bf16x8 ak1 = *(const bf16x8*)&Ks[(row * 8 + ((q8 + 4) ^ cc7)) * 8];
      ci = __builtin_amdgcn_mfma_f32_16x16x32_bf16(ak0, bq0, ci, 0, 0, 0);
      sc[nt] = __builtin_amdgcn_mfma_f32_16x16x32_bf16(ak1, bq1, ci, 0, 0, 0);
    }
    // online softmax (per-lane state for query c; reduce across q8 groups)
    float mx = sc[0][0];
#pragma unroll
    for (int nt = 0; nt < 4; ++nt)
#pragma unroll
      for (int r = 0; r < 4; ++r) mx = fmaxf(mx, sc[nt][r]);
    mx = fmaxf(mx, __shfl_xor(mx, 16));
    mx = fmaxf(mx, __shfl_xor(mx, 32));
    float mn = fmaxf(m_st, mx);
    float al = __builtin_amdgcn_exp2f(m_st - mn);
    float su = 0.0f;
    f16x4 pf[4];
#pragma unroll
    for (int nt = 0; nt < 4; ++nt)
#pragma unroll
      for (int r = 0; r < 4; ++r) {
        float p = __builtin_amdgcn_exp2f(sc[nt][r] - mn);
        su += p;
        pf[nt][r] = (_Float16)p;
      }
    su += __shfl_xor(su, 16);
    su += __shfl_xor(su, 32);
    l_st = l_st * al + su;
    m_st = mn;
#pragma unroll
    for (int i = 0; i < 4; ++i) o[i] *= al;
    // O^T += V^T . P^T  (x16 fp16; P straight from accumulators)
#pragma unroll
    for (int i = 0; i < 4; ++i) {
      const int row = i * 16 + c;
      f16x8 v01 = *(const f16x8*)&Vs[(row * 8 + ((2 * q8) ^ cc7)) * 8];
      f16x8 v23 = *(const f16x8*)&Vs[(row * 8 + ((2 * q8 + 1) ^ cc7)) * 8];
      f16x4 a0 = {v01[0], v01[1], v01[2], v01[3]};
      f16x4 a1 = {v01[4], v01[5], v01[6], v01[7]};
      f16x4 a2 = {v23[0], v23[1], v23[2], v23[3]};
      f16x4 a3 = {v23[4], v23[5], v23[6], v23[7]};
      o[i] = __builtin_amdgcn_mfma_f32_16x16x16f16(a0, pf[0], o[i], 0, 0, 0);
      o[i] = __builtin_amdgcn_mfma_f32_16x16x16f16(a1, pf[1], o[i], 0, 0, 0);
      o[i] = __builtin_amdgcn_mfma_f32_16x16x16f16(a2, pf[2], o[i], 0, 0, 0);
      o[i] = __builtin_amdgcn_mfma_f32_16x16x16f16(a3, pf[3], o[i], 0, 0, 0);
    }
  }
  // epilogue: lane holds O^T[d = 16i+4q8+r][query c]
  const int bidx = bh >> 3, h = bh & 7;
  float inv = 1.0f / l_st;
  size_t base = (size_t)(bidx * 1024 + ql) * 512 + h * 64;
#pragma unroll
  for (int i = 0; i < 4; ++i) {
    ushort4 ov4;
    ov4.x = f2b(o[i][0] * inv);
    ov4.y = f2b(o[i][1] * inv);
    ov4.z = f2b(o[i][2] * inv);
    ov4.w = f2b(o[i][3] * inv);
    *(ushort4*)(attn_out + base + i * 16 + q8 * 4) = ov4;
  }
}

extern "C" void kernel_launch(void* const* d_in, const int* in_sizes, int n_in,
                              void* d_out, int out_size, void* d_ws, size_t ws_size,
                              hipStream_t stream) {
  const float* x      = (const float*)d_in[0];
  const float* gamma  = (const float*)d_in[1];
  const float* beta   = (const float*)d_in[2];
  const float* w_qkv  = (const float*)d_in[3];
  const float* b_qkv  = (const float*)d_in[4];
  const float* w_pos  = (const float*)d_in[5];
  const float* w_out  = (const float*)d_in[6];
  const float* b_out  = (const float*)d_in[7];
  const float* u_bias = (const float*)d_in[8];
  const float* v_bias = (const float*)d_in[9];
  float* out = (float*)d_out;

  unsigned short* wsu = (unsigned short*)d_ws;
  unsigned short* xnb   = wsu;                    // 4M ushort
  unsigned short* peb   = wsu + 4194304;          // 512K
  unsigned short* wqkvb = wsu + 4718592;          // 768K
  unsigned short* wposb = wsu + 5505024;          // 256K
  unsigned short* woutb = wsu + 5767168;          // 256K
  unsigned short* qbf   = wsu + 6291456;          // 4M (bf16, pre-scaled)
  unsigned short* kbf   = wsu + 10485760;         // 4M (K' bf16 after fold)
  unsigned short* vbf   = wsu + 14680064;         // 4M (fp16)
  unsigned short* vtb   = wsu + 18874368;         // 4M (fp16, permuted-transposed)
  unsigned short* attnb = wsu + 23068672;         // 4M (bf16)
  float* posb  = (float*)(wsu + 27262976);        // 512K floats
  float* biasb = (float*)(wsu + 28311552);        // 64K floats (pre-scaled)

  prep1<<<11520, 256, 0, stream>>>(x, gamma, beta, xnb, peb,
                                   w_qkv, wqkvb, w_pos, wposb, w_out, woutb);
  // QKV GEMM (by<128, 128x24 blocks of 64x64) + pos GEMM (by>=128, bx<8) in one dispatch
  gemm_mfma<<<dim3(24, 144), 256, 0, stream>>>(xnb, wqkvb, b_qkv, nullptr, qbf, kbf, vbf,
                                               peb, wposb, posb, 512, 0);
  prep2<<<17408, 256, 0, stream>>>(kbf, posb, u_bias, v_bias, biasb, vbf, vtb);
  flash_mfma<<<dim3(16, 64), 256, 0, stream>>>(qbf, kbf, vtb, biasb, attnb);
  gemm_mfma<<<dim3(8, 128), 256, 0, stream>>>(attnb, woutb, b_out, out, nullptr, nullptr, nullptr,
                                              nullptr, nullptr, nullptr, 512, 2);
}

// Round 8
// 177.773 us; speedup vs baseline: 1.8141x; 1.0566x over previous
//
#include <hip/hip_runtime.h>
#include <math.h>

static constexpr int Bn = 8, Ln = 1024, Dm = 512, Hn = 8, DhN = 64;

typedef short bf16x8 __attribute__((ext_vector_type(8)));
typedef float f32x4 __attribute__((ext_vector_type(4)));
typedef _Float16 f16x4 __attribute__((ext_vector_type(4)));
typedef _Float16 f16x8 __attribute__((ext_vector_type(8)));
typedef unsigned int u32x4 __attribute__((ext_vector_type(4)));

// 0.125 * log2(e): folds the 1/sqrt(dh) scale AND the exp->exp2 conversion
#define QSCALE 0.1803368801111137f

static __device__ __forceinline__ unsigned short f2b(float f) {
  union { float f; unsigned int u; } x;
  x.f = f;
  unsigned int u = x.u;
  unsigned int r = (u + 0x7FFFu + ((u >> 16) & 1u)) >> 16;  // RNE
  return (unsigned short)r;
}
static __device__ __forceinline__ float b2f(unsigned short u) {
  union { unsigned int u; float f; } x;
  x.u = ((unsigned int)u) << 16;
  return x.f;
}

#define GLDS16(g, l)                                                        \
  __builtin_amdgcn_global_load_lds((const __attribute__((address_space(1))) void*)(g), \
                                   (__attribute__((address_space(3))) void*)(l), 16, 0, 0)

// ---------------- prep1: LayerNorm + PE + weight conversions (one dispatch) ----------------
__global__ __launch_bounds__(256) void prep1(const float* __restrict__ x,
                                             const float* __restrict__ gamma,
                                             const float* __restrict__ beta,
                                             unsigned short* __restrict__ xn,
                                             unsigned short* __restrict__ pe,
                                             const float* __restrict__ wq, unsigned short* __restrict__ wqb,
                                             const float* __restrict__ wp, unsigned short* __restrict__ wpb,
                                             const float* __restrict__ wo, unsigned short* __restrict__ wob) {
  int b = blockIdx.x;
  int t = threadIdx.x;
  if (b < 8192) {
    // LayerNorm row b
    const float2 v = *(const float2*)(x + (size_t)b * Dm + t * 2);
    float s = v.x + v.y;
    float sq = v.x * v.x + v.y * v.y;
#pragma unroll
    for (int off = 32; off > 0; off >>= 1) {
      s += __shfl_down(s, off);
      sq += __shfl_down(sq, off);
    }
    __shared__ float red[8];
    int wave = t >> 6, lane = t & 63;
    if (lane == 0) { red[wave * 2] = s; red[wave * 2 + 1] = sq; }
    __syncthreads();
    float S = red[0] + red[2] + red[4] + red[6];
    float SQ = red[1] + red[3] + red[5] + red[7];
    float mu = S * (1.0f / Dm);
    float var = SQ * (1.0f / Dm) - mu * mu;
    float rstd = rsqrtf(var + 1e-5f);
    int c = t * 2;
    ushort2 o;
    o.x = f2b((v.x - mu) * rstd * gamma[c] + beta[c]);
    o.y = f2b((v.y - mu) * rstd * gamma[c + 1] + beta[c + 1]);
    *(ushort2*)(xn + (size_t)b * Dm + c) = o;
  } else if (b < 10240) {
    int idx = (b - 8192) * 256 + t;
    int l = idx >> 9, k = idx & 511;
    float freq = expf(-0.0359778921f * (float)k);
    float angle = (float)(l - k) * freq;
    pe[idx] = f2b((k & 1) ? sinf(angle) : cosf(angle));
  } else {
    int cb = b - 10240;  // 0..1279
    const float* src;
    unsigned short* dst;
    int off;
    if (cb < 768) { src = wq; dst = wqb; off = cb; }
    else if (cb < 1024) { src = wp; dst = wpb; off = cb - 768; }
    else { src = wo; dst = wob; off = cb - 1024; }
    int i = off * 256 + t;
    float4 v = *(const float4*)(src + (size_t)i * 4);
    ushort4 o;
    o.x = f2b(v.x); o.y = f2b(v.y); o.z = f2b(v.z); o.w = f2b(v.w);
    *(ushort4*)(dst + (size_t)i * 4) = o;
  }
}

// ---------------- bf16 MFMA NT GEMM: 64x64 tile, DMA staging, high-TLP ----------------
// Blocks with blockIdx.y >= 128 run the small pos GEMM (A2/B2 -> outf2, mode 1, bx<8).
// mode 0: scatter q (bf16, pre-scaled) / k (bf16) / v (fp16) in (B,H,L,Dh)
// mode 1: posb f32 (H,L,Dh); mode 2: outf f32 row-major (N=512).
__global__ __launch_bounds__(256, 8) void gemm_mfma(const unsigned short* __restrict__ Ain,
                                                    const unsigned short* __restrict__ Bwin,
                                                    const float* __restrict__ biasin,
                                                    float* __restrict__ outfin,
                                                    unsigned short* __restrict__ oq,
                                                    unsigned short* __restrict__ ok,
                                                    unsigned short* __restrict__ ov,
                                                    const unsigned short* __restrict__ A2,
                                                    const unsigned short* __restrict__ B2,
                                                    float* __restrict__ outf2,
                                                    int K, int mode) {
  int by = blockIdx.y, bx = blockIdx.x;
  const unsigned short* A = Ain;
  const unsigned short* Bw = Bwin;
  const float* bias = biasin;
  float* outf = outfin;
  if (by >= 128) {
    if (bx >= 8) return;
    A = A2; Bw = B2; bias = nullptr; outf = outf2; mode = 1; by -= 128;
  }
  __shared__ alignas(16) unsigned short As[64 * 64];
  __shared__ alignas(16) unsigned short Bs[64 * 64];
  const int t = threadIdx.x;
  const int lane = t & 63, w = t >> 6;
  const int c = lane & 15, q8 = lane >> 4;
  const int wm = (w & 1) * 32, wn = (w >> 1) * 32;
  const int m0 = by * 64, n0 = bx * 64;

  f32x4 acc[2][2];
#pragma unroll
  for (int i = 0; i < 2; ++i)
#pragma unroll
    for (int j = 0; j < 2; ++j) acc[i][j] = (f32x4){0.f, 0.f, 0.f, 0.f};

  const int srow = lane >> 3;
  const int sgr = (lane & 7) ^ srow;

  for (int k0 = 0; k0 < K; k0 += 64) {
    __syncthreads();
#pragma unroll
    for (int j = 0; j < 2; ++j) {
      int r = j * 32 + w * 8 + srow;
      GLDS16(A + (size_t)(m0 + r) * K + k0 + sgr * 8, As + (j * 256 + w * 64 + lane) * 8);
      GLDS16(Bw + (size_t)(n0 + r) * K + k0 + sgr * 8, Bs + (j * 256 + w * 64 + lane) * 8);
    }
    __syncthreads();
#pragma unroll
    for (int kk = 0; kk < 2; ++kk) {
      bf16x8 a[2], b[2];
      const int q = kk * 4 + q8;
#pragma unroll
      for (int i = 0; i < 2; ++i) {
        int r = wm + i * 16 + c;
        a[i] = *(const bf16x8*)&As[(r * 8 + (q ^ (r & 7))) * 8];
      }
#pragma unroll
      for (int j = 0; j < 2; ++j) {
        int r = wn + j * 16 + c;
        b[j] = *(const bf16x8*)&Bs[(r * 8 + (q ^ (r & 7))) * 8];
      }
#pragma unroll
      for (int i = 0; i < 2; ++i)
#pragma unroll
        for (int j = 0; j < 2; ++j)
          acc[i][j] = __builtin_amdgcn_mfma_f32_16x16x32_bf16(a[i], b[j], acc[i][j], 0, 0, 0);
    }
  }
#pragma unroll
  for (int i = 0; i < 2; ++i) {
#pragma unroll
    for (int r = 0; r < 4; ++r) {
      int m = m0 + wm + i * 16 + q8 * 4 + r;
#pragma unroll
      for (int j = 0; j < 2; ++j) {
        int n = n0 + wn + j * 16 + c;
        float val = acc[i][j][r] + (bias ? bias[n] : 0.0f);
        if (mode == 0) {
          int part = n >> 9, h = (n >> 6) & 7, dh = n & 63;
          int bb = m >> 10, l = m & 1023;
          size_t idx = (size_t)((bb * 8 + h) * 1024 + l) * 64 + dh;
          if (part == 0) {
            oq[idx] = f2b(val * QSCALE);
          } else if (part == 1) {
            ok[idx] = f2b(val);
          } else {
            union { _Float16 h; unsigned short u; } cv;
            cv.h = (_Float16)val;
            ov[idx] = cv.u;
          }
        } else if (mode == 1) {
          int h = n >> 6, dh = n & 63;
          outf[(size_t)(h * 1024 + m) * 64 + dh] = val;
        } else {
          outf[(size_t)m * 512 + n] = val;
        }
      }
    }
  }
}

// ---------------- prep2: fold (K'=k+pos, bias) + V transpose-permute (one dispatch) ----------------
__global__ __launch_bounds__(256) void prep2(unsigned short* __restrict__ kbuf,
                                             const float* __restrict__ pos,
                                             const float* __restrict__ ub,
                                             const float* __restrict__ vbb,
                                             float* __restrict__ biasout,
                                             const unsigned short* __restrict__ v,
                                             unsigned short* __restrict__ vt) {
  int b = blockIdx.x;
  int t = threadIdx.x;
  if (b < 16384) {
    int wave = t >> 6, lane = t & 63;
    int g = b * 4 + wave;  // [0, B*H*L)
    int h = (g >> 10) & 7;
    int m = g & 1023;
    float kv = b2f(kbuf[(size_t)g * 64 + lane]);
    float pv = pos[(size_t)(h * 1024 + m) * 64 + lane];
    float val = ub[h * 64 + lane] * kv + vbb[h * 64 + lane] * pv;
#pragma unroll
    for (int off = 32; off > 0; off >>= 1) val += __shfl_down(val, off);
    if (lane == 0) biasout[g] = val * QSCALE;
    kbuf[(size_t)g * 64 + lane] = f2b(kv + pv);
  } else {
    // V fp16 (b,h,l,d) -> V2 fp16 (b,h,d,perm(l)); perm: dst = ((l>>2)&3)*16 + ((l>>4)&3)*4 + (l&3)
    __shared__ unsigned short Ts[64 * 68];
    int bb = b - 16384;
    int bh = bb >> 4, lt = bb & 15;
    const unsigned short* vg = v + (size_t)bh * 65536 + lt * 4096;
#pragma unroll
    for (int s = 0; s < 4; ++s) {
      int idx = t + s * 256;
      int r = idx >> 4, c4 = (idx & 15) << 2;
      *(ushort4*)&Ts[r * 68 + c4] = *(const ushort4*)(vg + r * 64 + c4);
    }
    __syncthreads();
#pragma unroll
    for (int s = 0; s < 4; ++s) {
      int idx = t + s * 256;
      int d = idx >> 4, l4 = (idx & 15) << 2;
      ushort4 o;
      o.x = Ts[(l4 + 0) * 68 + d];
      o.y = Ts[(l4 + 1) * 68 + d];
      o.z = Ts[(l4 + 2) * 68 + d];
      o.w = Ts[(l4 + 3) * 68 + d];
      int pb = ((l4 >> 2) & 3) * 16 + ((l4 >> 4) & 3) * 4;  // l4&3 == 0
      *(ushort4*)(vt + (size_t)bh * 65536 + d * 1024 + lt * 64 + pb) = o;
    }
  }
}

// ---------------- Flash attention v3: Q-tile 128 (8 waves), BK=128 (2 key-halves/iter) ----------------
// S^T = K'.Q^T (bf16 x32), O^T = V^T.P^T (fp16 x16), P stays in registers.
// grid (8, 64), 512 threads; wave w owns queries [16w, 16w+16) of the 128-row Q tile.
__global__ __launch_bounds__(512) void flash_mfma(const unsigned short* __restrict__ qbf,
                                                  const unsigned short* __restrict__ kbf,
                                                  const unsigned short* __restrict__ vt,
                                                  const float* __restrict__ bias,
                                                  unsigned short* __restrict__ attn_out) {
  __shared__ alignas(16) unsigned short Ks[2][64 * 64];  // key-halves; rows=key, swizzled granules over d
  __shared__ alignas(16) unsigned short Vs[2][64 * 64];  // key-halves; rows=d, swizzled granules over perm(key)
  __shared__ alignas(16) float Bls[1024];
  const int t = threadIdx.x;
  const int lane = t & 63, w = t >> 6;              // w in [0,8)
  const int c = lane & 15, q8 = lane >> 4;
  const int cc7 = c & 7;
  const int bh = blockIdx.y, qt = blockIdx.x;
  const unsigned short* qg = qbf + (size_t)bh * 65536;
  const unsigned short* kg = kbf + (size_t)bh * 65536;
  const unsigned short* vg = vt + (size_t)bh * 65536;
  const float* bg = bias + (size_t)bh * 1024;

  // stage bias once (4 KB): first 4 waves only
  if (t < 256) GLDS16(bg + t * 4, Bls + t * 4);

  const int ql = qt * 128 + w * 16 + c;
  const bf16x8 bq0 = *(const bf16x8*)(qg + (size_t)ql * 64 + q8 * 8);
  const bf16x8 bq1 = *(const bf16x8*)(qg + (size_t)ql * 64 + 32 + q8 * 8);

  float m_st = -INFINITY, l_st = 0.0f;
  f32x4 o[4];
#pragma unroll
  for (int i = 0; i < 4; ++i) o[i] = (f32x4){0.f, 0.f, 0.f, 0.f};

  // staging geometry: 8 waves x 64 lanes cover 64 rows x 8 granules per array per inst.
  // row = w*8 + (lane>>3); slot = lane&7; source granule = slot ^ (row&7).
  const int srow = lane >> 3;
  const int sgr = (lane & 7) ^ srow;
  const int r0 = w * 8 + srow;  // in [0,64)

  // prefetch it=0 into VGPRs
  u32x4 pk[2], pv[2];
#pragma unroll
  for (int h = 0; h < 2; ++h) {
    pk[h] = *(const u32x4*)(kg + (size_t)(h * 64 + r0) * 64 + sgr * 8);
    pv[h] = *(const u32x4*)(vg + (size_t)r0 * 1024 + h * 64 + sgr * 8);
  }

  for (int it = 0; it < 8; ++it) {
    __syncthreads();  // prior iteration's LDS reads done
#pragma unroll
    for (int h = 0; h < 2; ++h) {
      *(u32x4*)&Ks[h][(r0 * 8 + (lane & 7)) * 8] = pk[h];
      *(u32x4*)&Vs[h][(r0 * 8 + (lane & 7)) * 8] = pv[h];
    }
    __syncthreads();
    // prefetch next iteration (latency overlaps compute below)
    if (it < 7) {
#pragma unroll
      for (int h = 0; h < 2; ++h) {
        pk[h] = *(const u32x4*)(kg + (size_t)((it + 1) * 128 + h * 64 + r0) * 64 + sgr * 8);
        pv[h] = *(const u32x4*)(vg + (size_t)r0 * 1024 + (it + 1) * 128 + h * 64 + sgr * 8);
      }
    }

    // S^T for both key-halves, bias as MFMA C-initializer
    f32x4 sc[2][4];
#pragma unroll
    for (int h = 0; h < 2; ++h) {
#pragma unroll
      for (int nt = 0; nt < 4; ++nt) {
        f32x4 ci = *(const f32x4*)&Bls[it * 128 + h * 64 + nt * 16 + q8 * 4];
        const int row = nt * 16 + c;
        bf16x8 ak0 = *(const bf16x8*)&Ks[h][(row * 8 + (q8 ^ cc7)) * 8];
        bf16x8 ak1 = *(const bf16x8*)&Ks[h][(row * 8 + ((q8 + 4) ^ cc7)) * 8];
        ci = __builtin_amdgcn_mfma_f32_16x16x32_bf16(ak0, bq0, ci, 0, 0, 0);
        sc[h][nt] = __builtin_amdgcn_mfma_f32_16x16x32_bf16(ak1, bq1, ci, 0, 0, 0);
      }
    }
    // online softmax over 128 keys (per-lane state for query c; reduce across q8 groups)
    float mx = sc[0][0][0];
#pragma unroll
    for (int h = 0; h < 2; ++h)
#pragma unroll
      for (int nt = 0; nt < 4; ++nt)
#pragma unroll
        for (int r = 0; r < 4; ++r) mx = fmaxf(mx, sc[h][nt][r]);
    mx = fmaxf(mx, __shfl_xor(mx, 16));
    mx = fmaxf(mx, __shfl_xor(mx, 32));
    float mn = fmaxf(m_st, mx);
    float al = __builtin_amdgcn_exp2f(m_st - mn);
    float su = 0.0f;
    f16x4 pf[2][4];
#pragma unroll
    for (int h = 0; h < 2; ++h)
#pragma unroll
      for (int nt = 0; nt < 4; ++nt)
#pragma unroll
        for (int r = 0; r < 4; ++r) {
          float p = __builtin_amdgcn_exp2f(sc[h][nt][r] - mn);
          su += p;
          pf[h][nt][r] = (_Float16)p;
        }
    su += __shfl_xor(su, 16);
    su += __shfl_xor(su, 32);
    l_st = l_st * al + su;
    m_st = mn;
#pragma unroll
    for (int i = 0; i < 4; ++i) o[i] *= al;
    // O^T += V^T . P^T  (x16 fp16; P straight from accumulators)
#pragma unroll
    for (int i = 0; i < 4; ++i) {
      const int row = i * 16 + c;
#pragma unroll
      for (int h = 0; h < 2; ++h) {
        f16x8 v01 = *(const f16x8*)&Vs[h][(row * 8 + ((2 * q8) ^ cc7)) * 8];
        f16x8 v23 = *(const f16x8*)&Vs[h][(row * 8 + ((2 * q8 + 1) ^ cc7)) * 8];
        f16x4 a0 = {v01[0], v01[1], v01[2], v01[3]};
        f16x4 a1 = {v01[4], v01[5], v01[6], v01[7]};
        f16x4 a2 = {v23[0], v23[1], v23[2], v23[3]};
        f16x4 a3 = {v23[4], v23[5], v23[6], v23[7]};
        o[i] = __builtin_amdgcn_mfma_f32_16x16x16f16(a0, pf[h][0], o[i], 0, 0, 0);
        o[i] = __builtin_amdgcn_mfma_f32_16x16x16f16(a1, pf[h][1], o[i], 0, 0, 0);
        o[i] = __builtin_amdgcn_mfma_f32_16x16x16f16(a2, pf[h][2], o[i], 0, 0, 0);
        o[i] = __builtin_amdgcn_mfma_f32_16x16x16f16(a3, pf[h][3], o[i], 0, 0, 0);
      }
    }
  }
  // epilogue: lane holds O^T[d = 16i+4q8+r][query c]
  const int bidx = bh >> 3, h = bh & 7;
  float inv = 1.0f / l_st;
  size_t base = (size_t)(bidx * 1024 + ql) * 512 + h * 64;
#pragma unroll
  for (int i = 0; i < 4; ++i) {
    ushort4 ov4;
    ov4.x = f2b(o[i][0] * inv);
    ov4.y = f2b(o[i][1] * inv);
    ov4.z = f2b(o[i][2] * inv);
    ov4.w = f2b(o[i][3] * inv);
    *(ushort4*)(attn_out + base + i * 16 + q8 * 4) = ov4;
  }
}

extern "C" void kernel_launch(void* const* d_in, const int* in_sizes, int n_in,
                              void* d_out, int out_size, void* d_ws, size_t ws_size,
                              hipStream_t stream) {
  const float* x      = (const float*)d_in[0];
  const float* gamma  = (const float*)d_in[1];
  const float* beta   = (const float*)d_in[2];
  const float* w_qkv  = (const float*)d_in[3];
  const float* b_qkv  = (const float*)d_in[4];
  const float* w_pos  = (const float*)d_in[5];
  const float* w_out  = (const float*)d_in[6];
  const float* b_out  = (const float*)d_in[7];
  const float* u_bias = (const float*)d_in[8];
  const float* v_bias = (const float*)d_in[9];
  float* out = (float*)d_out;

  unsigned short* wsu = (unsigned short*)d_ws;
  unsigned short* xnb   = wsu;                    // 4M ushort
  unsigned short* peb   = wsu + 4194304;          // 512K
  unsigned short* wqkvb = wsu + 4718592;          // 768K
  unsigned short* wposb = wsu + 5505024;          // 256K
  unsigned short* woutb = wsu + 5767168;          // 256K
  unsigned short* qbf   = wsu + 6291456;          // 4M (bf16, pre-scaled)
  unsigned short* kbf   = wsu + 10485760;         // 4M (K' bf16 after fold)
  unsigned short* vbf   = wsu + 14680064;         // 4M (fp16)
  unsigned short* vtb   = wsu + 18874368;         // 4M (fp16, permuted-transposed)
  unsigned short* attnb = wsu + 23068672;         // 4M (bf16)
  float* posb  = (float*)(wsu + 27262976);        // 512K floats
  float* biasb = (float*)(wsu + 28311552);        // 64K floats (pre-scaled)

  prep1<<<11520, 256, 0, stream>>>(x, gamma, beta, xnb, peb,
                                   w_qkv, wqkvb, w_pos, wposb, w_out, woutb);
  // QKV GEMM (by<128, 128x24 blocks of 64x64) + pos GEMM (by>=128, bx<8) in one dispatch
  gemm_mfma<<<dim3(24, 144), 256, 0, stream>>>(xnb, wqkvb, b_qkv, nullptr, qbf, kbf, vbf,
                                               peb, wposb, posb, 512, 0);
  prep2<<<17408, 256, 0, stream>>>(kbf, posb, u_bias, v_bias, biasb, vbf, vtb);
  flash_mfma<<<dim3(8, 64), 512, 0, stream>>>(qbf, kbf, vtb, biasb, attnb);
  gemm_mfma<<<dim3(8, 128), 256, 0, stream>>>(attnb, woutb, b_out, out, nullptr, nullptr, nullptr,
                                              nullptr, nullptr, nullptr, 512, 2);
}

// Round 9
// 176.759 us; speedup vs baseline: 1.8246x; 1.0057x over previous
//
#include <hip/hip_runtime.h>
#include <math.h>

static constexpr int Bn = 8, Ln = 1024, Dm = 512, Hn = 8, DhN = 64;

typedef short bf16x8 __attribute__((ext_vector_type(8)));
typedef float f32x4 __attribute__((ext_vector_type(4)));
typedef _Float16 f16x4 __attribute__((ext_vector_type(4)));
typedef _Float16 f16x8 __attribute__((ext_vector_type(8)));
typedef unsigned int u32x4 __attribute__((ext_vector_type(4)));

// 0.125 * log2(e): folds the 1/sqrt(dh) scale AND the exp->exp2 conversion
#define QSCALE 0.1803368801111137f

static __device__ __forceinline__ unsigned short f2b(float f) {
  union { float f; unsigned int u; } x;
  x.f = f;
  unsigned int u = x.u;
  unsigned int r = (u + 0x7FFFu + ((u >> 16) & 1u)) >> 16;  // RNE
  return (unsigned short)r;
}
static __device__ __forceinline__ float b2f(unsigned short u) {
  union { unsigned int u; float f; } x;
  x.u = ((unsigned int)u) << 16;
  return x.f;
}

#define GLDS16(g, l)                                                        \
  __builtin_amdgcn_global_load_lds((const __attribute__((address_space(1))) void*)(g), \
                                   (__attribute__((address_space(3))) void*)(l), 16, 0, 0)

// ---------------- prep1: LayerNorm + PE + weight conversions (one dispatch) ----------------
__global__ __launch_bounds__(256) void prep1(const float* __restrict__ x,
                                             const float* __restrict__ gamma,
                                             const float* __restrict__ beta,
                                             unsigned short* __restrict__ xn,
                                             unsigned short* __restrict__ pe,
                                             const float* __restrict__ wq, unsigned short* __restrict__ wqb,
                                             const float* __restrict__ wp, unsigned short* __restrict__ wpb,
                                             const float* __restrict__ wo, unsigned short* __restrict__ wob) {
  int b = blockIdx.x;
  int t = threadIdx.x;
  if (b < 8192) {
    // LayerNorm row b
    const float2 v = *(const float2*)(x + (size_t)b * Dm + t * 2);
    float s = v.x + v.y;
    float sq = v.x * v.x + v.y * v.y;
#pragma unroll
    for (int off = 32; off > 0; off >>= 1) {
      s += __shfl_down(s, off);
      sq += __shfl_down(sq, off);
    }
    __shared__ float red[8];
    int wave = t >> 6, lane = t & 63;
    if (lane == 0) { red[wave * 2] = s; red[wave * 2 + 1] = sq; }
    __syncthreads();
    float S = red[0] + red[2] + red[4] + red[6];
    float SQ = red[1] + red[3] + red[5] + red[7];
    float mu = S * (1.0f / Dm);
    float var = SQ * (1.0f / Dm) - mu * mu;
    float rstd = rsqrtf(var + 1e-5f);
    int c = t * 2;
    ushort2 o;
    o.x = f2b((v.x - mu) * rstd * gamma[c] + beta[c]);
    o.y = f2b((v.y - mu) * rstd * gamma[c + 1] + beta[c + 1]);
    *(ushort2*)(xn + (size_t)b * Dm + c) = o;
  } else if (b < 10240) {
    int idx = (b - 8192) * 256 + t;
    int l = idx >> 9, k = idx & 511;
    float freq = expf(-0.0359778921f * (float)k);
    float angle = (float)(l - k) * freq;
    pe[idx] = f2b((k & 1) ? sinf(angle) : cosf(angle));
  } else {
    int cb = b - 10240;  // 0..1279
    const float* src;
    unsigned short* dst;
    int off;
    if (cb < 768) { src = wq; dst = wqb; off = cb; }
    else if (cb < 1024) { src = wp; dst = wpb; off = cb - 768; }
    else { src = wo; dst = wob; off = cb - 1024; }
    int i = off * 256 + t;
    float4 v = *(const float4*)(src + (size_t)i * 4);
    ushort4 o;
    o.x = f2b(v.x); o.y = f2b(v.y); o.z = f2b(v.z); o.w = f2b(v.w);
    *(ushort4*)(dst + (size_t)i * 4) = o;
  }
}

// ---------------- bf16 MFMA NT GEMM: 64x64 tile, DMA staging, high-TLP ----------------
// Blocks with blockIdx.y >= 128 run the small pos GEMM (A2/B2 -> outf2, mode 1, bx<8).
// mode 0: scatter q (bf16, pre-scaled) / k (bf16) / v (fp16) in (B,H,L,Dh)
// mode 1: posb f32 (H,L,Dh); mode 2: outf f32 row-major (N=512).
__global__ __launch_bounds__(256, 8) void gemm_mfma(const unsigned short* __restrict__ Ain,
                                                    const unsigned short* __restrict__ Bwin,
                                                    const float* __restrict__ biasin,
                                                    float* __restrict__ outfin,
                                                    unsigned short* __restrict__ oq,
                                                    unsigned short* __restrict__ ok,
                                                    unsigned short* __restrict__ ov,
                                                    const unsigned short* __restrict__ A2,
                                                    const unsigned short* __restrict__ B2,
                                                    float* __restrict__ outf2,
                                                    int K, int mode) {
  int by = blockIdx.y, bx = blockIdx.x;
  const unsigned short* A = Ain;
  const unsigned short* Bw = Bwin;
  const float* bias = biasin;
  float* outf = outfin;
  if (by >= 128) {
    if (bx >= 8) return;
    A = A2; Bw = B2; bias = nullptr; outf = outf2; mode = 1; by -= 128;
  }
  __shared__ alignas(16) unsigned short As[64 * 64];
  __shared__ alignas(16) unsigned short Bs[64 * 64];
  const int t = threadIdx.x;
  const int lane = t & 63, w = t >> 6;
  const int c = lane & 15, q8 = lane >> 4;
  const int wm = (w & 1) * 32, wn = (w >> 1) * 32;
  const int m0 = by * 64, n0 = bx * 64;

  f32x4 acc[2][2];
#pragma unroll
  for (int i = 0; i < 2; ++i)
#pragma unroll
    for (int j = 0; j < 2; ++j) acc[i][j] = (f32x4){0.f, 0.f, 0.f, 0.f};

  const int srow = lane >> 3;
  const int sgr = (lane & 7) ^ srow;

  for (int k0 = 0; k0 < K; k0 += 64) {
    __syncthreads();
#pragma unroll
    for (int j = 0; j < 2; ++j) {
      int r = j * 32 + w * 8 + srow;
      GLDS16(A + (size_t)(m0 + r) * K + k0 + sgr * 8, As + (j * 256 + w * 64 + lane) * 8);
      GLDS16(Bw + (size_t)(n0 + r) * K + k0 + sgr * 8, Bs + (j * 256 + w * 64 + lane) * 8);
    }
    __syncthreads();
#pragma unroll
    for (int kk = 0; kk < 2; ++kk) {
      bf16x8 a[2], b[2];
      const int q = kk * 4 + q8;
#pragma unroll
      for (int i = 0; i < 2; ++i) {
        int r = wm + i * 16 + c;
        a[i] = *(const bf16x8*)&As[(r * 8 + (q ^ (r & 7))) * 8];
      }
#pragma unroll
      for (int j = 0; j < 2; ++j) {
        int r = wn + j * 16 + c;
        b[j] = *(const bf16x8*)&Bs[(r * 8 + (q ^ (r & 7))) * 8];
      }
#pragma unroll
      for (int i = 0; i < 2; ++i)
#pragma unroll
        for (int j = 0; j < 2; ++j)
          acc[i][j] = __builtin_amdgcn_mfma_f32_16x16x32_bf16(a[i], b[j], acc[i][j], 0, 0, 0);
    }
  }
#pragma unroll
  for (int i = 0; i < 2; ++i) {
#pragma unroll
    for (int r = 0; r < 4; ++r) {
      int m = m0 + wm + i * 16 + q8 * 4 + r;
#pragma unroll
      for (int j = 0; j < 2; ++j) {
        int n = n0 + wn + j * 16 + c;
        float val = acc[i][j][r] + (bias ? bias[n] : 0.0f);
        if (mode == 0) {
          int part = n >> 9, h = (n >> 6) & 7, dh = n & 63;
          int bb = m >> 10, l = m & 1023;
          size_t idx = (size_t)((bb * 8 + h) * 1024 + l) * 64 + dh;
          if (part == 0) {
            oq[idx] = f2b(val * QSCALE);
          } else if (part == 1) {
            ok[idx] = f2b(val);
          } else {
            union { _Float16 h; unsigned short u; } cv;
            cv.h = (_Float16)val;
            ov[idx] = cv.u;
          }
        } else if (mode == 1) {
          int h = n >> 6, dh = n & 63;
          outf[(size_t)(h * 1024 + m) * 64 + dh] = val;
        } else {
          outf[(size_t)m * 512 + n] = val;
        }
      }
    }
  }
}

// ---------------- prep2: fold (K'=k+pos, bias) + V transpose-permute (one dispatch) ----------------
__global__ __launch_bounds__(256) void prep2(unsigned short* __restrict__ kbuf,
                                             const float* __restrict__ pos,
                                             const float* __restrict__ ub,
                                             const float* __restrict__ vbb,
                                             float* __restrict__ biasout,
                                             const unsigned short* __restrict__ v,
                                             unsigned short* __restrict__ vt) {
  int b = blockIdx.x;
  int t = threadIdx.x;
  if (b < 16384) {
    int wave = t >> 6, lane = t & 63;
    int g = b * 4 + wave;  // [0, B*H*L)
    int h = (g >> 10) & 7;
    int m = g & 1023;
    float kv = b2f(kbuf[(size_t)g * 64 + lane]);
    float pv = pos[(size_t)(h * 1024 + m) * 64 + lane];
    float val = ub[h * 64 + lane] * kv + vbb[h * 64 + lane] * pv;
#pragma unroll
    for (int off = 32; off > 0; off >>= 1) val += __shfl_down(val, off);
    if (lane == 0) biasout[g] = val * QSCALE;
    kbuf[(size_t)g * 64 + lane] = f2b(kv + pv);
  } else {
    // V fp16 (b,h,l,d) -> V2 fp16 (b,h,d,perm(l)); perm: dst = ((l>>2)&3)*16 + ((l>>4)&3)*4 + (l&3)
    __shared__ unsigned short Ts[64 * 68];
    int bb = b - 16384;
    int bh = bb >> 4, lt = bb & 15;
    const unsigned short* vg = v + (size_t)bh * 65536 + lt * 4096;
#pragma unroll
    for (int s = 0; s < 4; ++s) {
      int idx = t + s * 256;
      int r = idx >> 4, c4 = (idx & 15) << 2;
      *(ushort4*)&Ts[r * 68 + c4] = *(const ushort4*)(vg + r * 64 + c4);
    }
    __syncthreads();
#pragma unroll
    for (int s = 0; s < 4; ++s) {
      int idx = t + s * 256;
      int d = idx >> 4, l4 = (idx & 15) << 2;
      ushort4 o;
      o.x = Ts[(l4 + 0) * 68 + d];
      o.y = Ts[(l4 + 1) * 68 + d];
      o.z = Ts[(l4 + 2) * 68 + d];
      o.w = Ts[(l4 + 3) * 68 + d];
      int pb = ((l4 >> 2) & 3) * 16 + ((l4 >> 4) & 3) * 4;  // l4&3 == 0
      *(ushort4*)(vt + (size_t)bh * 65536 + d * 1024 + lt * 64 + pb) = o;
    }
  }
}

// ---------------- Flash attention v4: Q-tile 128 = 4 waves x 2 query-groups, BK=128 ----------------
// S^T = K'.Q^T (bf16 x32), O^T = V^T.P^T (fp16 x16), P stays in registers.
// K/V/bias LDS reads are query-group-independent -> each b128 read feeds 2 MFMAs.
// grid (8, 64), 256 threads; wave w owns queries {w*16+c, 64+w*16+c}.
__global__ __launch_bounds__(256, 2) void flash_mfma(const unsigned short* __restrict__ qbf,
                                                     const unsigned short* __restrict__ kbf,
                                                     const unsigned short* __restrict__ vt,
                                                     const float* __restrict__ bias,
                                                     unsigned short* __restrict__ attn_out) {
  __shared__ alignas(16) unsigned short Ks[2][64 * 64];  // key-halves; rows=key, swizzled granules over d
  __shared__ alignas(16) unsigned short Vs[2][64 * 64];  // key-halves; rows=d, swizzled granules over perm(key)
  __shared__ alignas(16) float Bls[1024];
  const int t = threadIdx.x;
  const int lane = t & 63, w = t >> 6;              // w in [0,4)
  const int c = lane & 15, q8 = lane >> 4;
  const int cc7 = c & 7;
  const int bh = blockIdx.y, qt = blockIdx.x;
  const unsigned short* qg = qbf + (size_t)bh * 65536;
  const unsigned short* kg = kbf + (size_t)bh * 65536;
  const unsigned short* vg = vt + (size_t)bh * 65536;
  const float* bg = bias + (size_t)bh * 1024;

  // stage bias once (4 KB): 256 threads x 16 B
  GLDS16(bg + t * 4, Bls + t * 4);

  // Q for both query groups, register-resident
  bf16x8 bq[2][2];
#pragma unroll
  for (int g = 0; g < 2; ++g) {
    int qlg = qt * 128 + g * 64 + w * 16 + c;
    bq[g][0] = *(const bf16x8*)(qg + (size_t)qlg * 64 + q8 * 8);
    bq[g][1] = *(const bf16x8*)(qg + (size_t)qlg * 64 + 32 + q8 * 8);
  }

  float m_st[2] = {-INFINITY, -INFINITY}, l_st[2] = {0.0f, 0.0f};
  f32x4 o[2][4];
#pragma unroll
  for (int g = 0; g < 2; ++g)
#pragma unroll
    for (int i = 0; i < 4; ++i) o[g][i] = (f32x4){0.f, 0.f, 0.f, 0.f};

  // staging geometry: 4 waves x 64 lanes x 2 row-sets cover 64 rows x 8 granules per array half.
  // row = w*16 + j*8 + (lane>>3); slot = lane&7; source granule = slot ^ (row&7).
  const int srow = lane >> 3;
  const int sgr = (lane & 7) ^ srow;
  const int r0 = w * 16 + srow;  // rows r0, r0+8

  // prefetch it=0 into VGPRs
  u32x4 pk[2][2], pv[2][2];
#pragma unroll
  for (int h = 0; h < 2; ++h)
#pragma unroll
    for (int j = 0; j < 2; ++j) {
      int r = r0 + j * 8;
      pk[h][j] = *(const u32x4*)(kg + (size_t)(h * 64 + r) * 64 + sgr * 8);
      pv[h][j] = *(const u32x4*)(vg + (size_t)r * 1024 + h * 64 + sgr * 8);
    }

  for (int it = 0; it < 8; ++it) {
    __syncthreads();  // prior iteration's LDS reads done
#pragma unroll
    for (int h = 0; h < 2; ++h)
#pragma unroll
      for (int j = 0; j < 2; ++j) {
        int r = r0 + j * 8;
        *(u32x4*)&Ks[h][(r * 8 + (lane & 7)) * 8] = pk[h][j];
        *(u32x4*)&Vs[h][(r * 8 + (lane & 7)) * 8] = pv[h][j];
      }
    __syncthreads();
    // prefetch next iteration (latency overlaps compute below)
    if (it < 7) {
#pragma unroll
      for (int h = 0; h < 2; ++h)
#pragma unroll
        for (int j = 0; j < 2; ++j) {
          int r = r0 + j * 8;
          pk[h][j] = *(const u32x4*)(kg + (size_t)((it + 1) * 128 + h * 64 + r) * 64 + sgr * 8);
          pv[h][j] = *(const u32x4*)(vg + (size_t)r * 1024 + (it + 1) * 128 + h * 64 + sgr * 8);
        }
    }

    // S^T for both key-halves and both query groups; K-frag + bias reads shared across groups
    f32x4 sc[2][2][4];
#pragma unroll
    for (int h = 0; h < 2; ++h) {
#pragma unroll
      for (int nt = 0; nt < 4; ++nt) {
        f32x4 ci = *(const f32x4*)&Bls[it * 128 + h * 64 + nt * 16 + q8 * 4];
        const int row = nt * 16 + c;
        bf16x8 ak0 = *(const bf16x8*)&Ks[h][(row * 8 + (q8 ^ cc7)) * 8];
        bf16x8 ak1 = *(const bf16x8*)&Ks[h][(row * 8 + ((q8 + 4) ^ cc7)) * 8];
#pragma unroll
        for (int g = 0; g < 2; ++g) {
          f32x4 z = __builtin_amdgcn_mfma_f32_16x16x32_bf16(ak0, bq[g][0], ci, 0, 0, 0);
          sc[g][h][nt] = __builtin_amdgcn_mfma_f32_16x16x32_bf16(ak1, bq[g][1], z, 0, 0, 0);
        }
      }
    }
    // online softmax per group (per-lane state for query c; reduce across q8 groups)
    f16x4 pf[2][2][4];
#pragma unroll
    for (int g = 0; g < 2; ++g) {
      float mx = sc[g][0][0][0];
#pragma unroll
      for (int h = 0; h < 2; ++h)
#pragma unroll
        for (int nt = 0; nt < 4; ++nt)
#pragma unroll
          for (int r = 0; r < 4; ++r) mx = fmaxf(mx, sc[g][h][nt][r]);
      mx = fmaxf(mx, __shfl_xor(mx, 16));
      mx = fmaxf(mx, __shfl_xor(mx, 32));
      float mn = fmaxf(m_st[g], mx);
      float al = __builtin_amdgcn_exp2f(m_st[g] - mn);
      float su = 0.0f;
#pragma unroll
      for (int h = 0; h < 2; ++h)
#pragma unroll
        for (int nt = 0; nt < 4; ++nt)
#pragma unroll
          for (int r = 0; r < 4; ++r) {
            float p = __builtin_amdgcn_exp2f(sc[g][h][nt][r] - mn);
            su += p;
            pf[g][h][nt][r] = (_Float16)p;
          }
      su += __shfl_xor(su, 16);
      su += __shfl_xor(su, 32);
      l_st[g] = l_st[g] * al + su;
      m_st[g] = mn;
#pragma unroll
      for (int i = 0; i < 4; ++i) o[g][i] *= al;
    }
    // O^T += V^T . P^T  (x16 fp16; V-frag reads shared across groups)
#pragma unroll
    for (int i = 0; i < 4; ++i) {
      const int row = i * 16 + c;
#pragma unroll
      for (int h = 0; h < 2; ++h) {
        f16x8 v01 = *(const f16x8*)&Vs[h][(row * 8 + ((2 * q8) ^ cc7)) * 8];
        f16x8 v23 = *(const f16x8*)&Vs[h][(row * 8 + ((2 * q8 + 1) ^ cc7)) * 8];
        f16x4 a0 = {v01[0], v01[1], v01[2], v01[3]};
        f16x4 a1 = {v01[4], v01[5], v01[6], v01[7]};
        f16x4 a2 = {v23[0], v23[1], v23[2], v23[3]};
        f16x4 a3 = {v23[4], v23[5], v23[6], v23[7]};
#pragma unroll
        for (int g = 0; g < 2; ++g) {
          o[g][i] = __builtin_amdgcn_mfma_f32_16x16x16f16(a0, pf[g][h][0], o[g][i], 0, 0, 0);
          o[g][i] = __builtin_amdgcn_mfma_f32_16x16x16f16(a1, pf[g][h][1], o[g][i], 0, 0, 0);
          o[g][i] = __builtin_amdgcn_mfma_f32_16x16x16f16(a2, pf[g][h][2], o[g][i], 0, 0, 0);
          o[g][i] = __builtin_amdgcn_mfma_f32_16x16x16f16(a3, pf[g][h][3], o[g][i], 0, 0, 0);
        }
      }
    }
  }
  // epilogue: lane holds O^T[d = 16i+4q8+r][query] for both groups
  const int bidx = bh >> 3, h = bh & 7;
#pragma unroll
  for (int g = 0; g < 2; ++g) {
    int qlg = qt * 128 + g * 64 + w * 16 + c;
    float inv = 1.0f / l_st[g];
    size_t base = (size_t)(bidx * 1024 + qlg) * 512 + h * 64;
#pragma unroll
    for (int i = 0; i < 4; ++i) {
      ushort4 ov4;
      ov4.x = f2b(o[g][i][0] * inv);
      ov4.y = f2b(o[g][i][1] * inv);
      ov4.z = f2b(o[g][i][2] * inv);
      ov4.w = f2b(o[g][i][3] * inv);
      *(ushort4*)(attn_out + base + i * 16 + q8 * 4) = ov4;
    }
  }
}

extern "C" void kernel_launch(void* const* d_in, const int* in_sizes, int n_in,
                              void* d_out, int out_size, void* d_ws, size_t ws_size,
                              hipStream_t stream) {
  const float* x      = (const float*)d_in[0];
  const float* gamma  = (const float*)d_in[1];
  const float* beta   = (const float*)d_in[2];
  const float* w_qkv  = (const float*)d_in[3];
  const float* b_qkv  = (const float*)d_in[4];
  const float* w_pos  = (const float*)d_in[5];
  const float* w_out  = (const float*)d_in[6];
  const float* b_out  = (const float*)d_in[7];
  const float* u_bias = (const float*)d_in[8];
  const float* v_bias = (const float*)d_in[9];
  float* out = (float*)d_out;

  unsigned short* wsu = (unsigned short*)d_ws;
  unsigned short* xnb   = wsu;                    // 4M ushort
  unsigned short* peb   = wsu + 4194304;          // 512K
  unsigned short* wqkvb = wsu + 4718592;          // 768K
  unsigned short* wposb = wsu + 5505024;          // 256K
  unsigned short* woutb = wsu + 5767168;          // 256K
  unsigned short* qbf   = wsu + 6291456;          // 4M (bf16, pre-scaled)
  unsigned short* kbf   = wsu + 10485760;         // 4M (K' bf16 after fold)
  unsigned short* vbf   = wsu + 14680064;         // 4M (fp16)
  unsigned short* vtb   = wsu + 18874368;         // 4M (fp16, permuted-transposed)
  unsigned short* attnb = wsu + 23068672;         // 4M (bf16)
  float* posb  = (float*)(wsu + 27262976);        // 512K floats
  float* biasb = (float*)(wsu + 28311552);        // 64K floats (pre-scaled)

  prep1<<<11520, 256, 0, stream>>>(x, gamma, beta, xnb, peb,
                                   w_qkv, wqkvb, w_pos, wposb, w_out, woutb);
  // QKV GEMM (by<128, 128x24 blocks of 64x64) + pos GEMM (by>=128, bx<8) in one dispatch
  gemm_mfma<<<dim3(24, 144), 256, 0, stream>>>(xnb, wqkvb, b_qkv, nullptr, qbf, kbf, vbf,
                                               peb, wposb, posb, 512, 0);
  prep2<<<17408, 256, 0, stream>>>(kbf, posb, u_bias, v_bias, biasb, vbf, vtb);
  flash_mfma<<<dim3(8, 64), 256, 0, stream>>>(qbf, kbf, vtb, biasb, attnb);
  gemm_mfma<<<dim3(8, 128), 256, 0, stream>>>(attnb, woutb, b_out, out, nullptr, nullptr, nullptr,
                                              nullptr, nullptr, nullptr, 512, 2);
}

// Round 10
// 175.744 us; speedup vs baseline: 1.8351x; 1.0058x over previous
//
#include <hip/hip_runtime.h>
#include <math.h>

static constexpr int Bn = 8, Ln = 1024, Dm = 512, Hn = 8, DhN = 64;

typedef short bf16x8 __attribute__((ext_vector_type(8)));
typedef float f32x4 __attribute__((ext_vector_type(4)));
typedef _Float16 f16x4 __attribute__((ext_vector_type(4)));
typedef _Float16 f16x8 __attribute__((ext_vector_type(8)));
typedef unsigned int u32x4 __attribute__((ext_vector_type(4)));

// 0.125 * log2(e): folds the 1/sqrt(dh) scale AND the exp->exp2 conversion
#define QSCALE 0.1803368801111137f

static __device__ __forceinline__ unsigned short f2b(float f) {
  union { float f; unsigned int u; } x;
  x.f = f;
  unsigned int u = x.u;
  unsigned int r = (u + 0x7FFFu + ((u >> 16) & 1u)) >> 16;  // RNE
  return (unsigned short)r;
}
static __device__ __forceinline__ float b2f(unsigned short u) {
  union { unsigned int u; float f; } x;
  x.u = ((unsigned int)u) << 16;
  return x.f;
}

#define GLDS16(g, l)                                                        \
  __builtin_amdgcn_global_load_lds((const __attribute__((address_space(1))) void*)(g), \
                                   (__attribute__((address_space(3))) void*)(l), 16, 0, 0)

// ---------------- prep1: LayerNorm + PE + weight conversions (one dispatch) ----------------
__global__ __launch_bounds__(256) void prep1(const float* __restrict__ x,
                                             const float* __restrict__ gamma,
                                             const float* __restrict__ beta,
                                             unsigned short* __restrict__ xn,
                                             unsigned short* __restrict__ pe,
                                             const float* __restrict__ wq, unsigned short* __restrict__ wqb,
                                             const float* __restrict__ wp, unsigned short* __restrict__ wpb,
                                             const float* __restrict__ wo, unsigned short* __restrict__ wob) {
  int b = blockIdx.x;
  int t = threadIdx.x;
  if (b < 8192) {
    // LayerNorm row b
    const float2 v = *(const float2*)(x + (size_t)b * Dm + t * 2);
    float s = v.x + v.y;
    float sq = v.x * v.x + v.y * v.y;
#pragma unroll
    for (int off = 32; off > 0; off >>= 1) {
      s += __shfl_down(s, off);
      sq += __shfl_down(sq, off);
    }
    __shared__ float red[8];
    int wave = t >> 6, lane = t & 63;
    if (lane == 0) { red[wave * 2] = s; red[wave * 2 + 1] = sq; }
    __syncthreads();
    float S = red[0] + red[2] + red[4] + red[6];
    float SQ = red[1] + red[3] + red[5] + red[7];
    float mu = S * (1.0f / Dm);
    float var = SQ * (1.0f / Dm) - mu * mu;
    float rstd = rsqrtf(var + 1e-5f);
    int c = t * 2;
    ushort2 o;
    o.x = f2b((v.x - mu) * rstd * gamma[c] + beta[c]);
    o.y = f2b((v.y - mu) * rstd * gamma[c + 1] + beta[c + 1]);
    *(ushort2*)(xn + (size_t)b * Dm + c) = o;
  } else if (b < 10240) {
    int idx = (b - 8192) * 256 + t;
    int l = idx >> 9, k = idx & 511;
    float freq = expf(-0.0359778921f * (float)k);
    float angle = (float)(l - k) * freq;
    pe[idx] = f2b((k & 1) ? sinf(angle) : cosf(angle));
  } else {
    int cb = b - 10240;  // 0..1279
    const float* src;
    unsigned short* dst;
    int off;
    if (cb < 768) { src = wq; dst = wqb; off = cb; }
    else if (cb < 1024) { src = wp; dst = wpb; off = cb - 768; }
    else { src = wo; dst = wob; off = cb - 1024; }
    int i = off * 256 + t;
    float4 v = *(const float4*)(src + (size_t)i * 4);
    ushort4 o;
    o.x = f2b(v.x); o.y = f2b(v.y); o.z = f2b(v.z); o.w = f2b(v.w);
    *(ushort4*)(dst + (size_t)i * 4) = o;
  }
}

// ---------------- bf16 MFMA NT GEMM: 64x64 tile, DMA staging, high-TLP ----------------
// Blocks with blockIdx.y >= 128 run the small pos GEMM (A2/B2 -> outf2, mode 1, bx<8).
// mode 0: scatter q (bf16, pre-scaled) / k (bf16) / v (fp16) in (B,H,L,Dh)
// mode 1: posb f32 (H,L,Dh); mode 2: outf f32 row-major (N=512).
__global__ __launch_bounds__(256, 8) void gemm_mfma(const unsigned short* __restrict__ Ain,
                                                    const unsigned short* __restrict__ Bwin,
                                                    const float* __restrict__ biasin,
                                                    float* __restrict__ outfin,
                                                    unsigned short* __restrict__ oq,
                                                    unsigned short* __restrict__ ok,
                                                    unsigned short* __restrict__ ov,
                                                    const unsigned short* __restrict__ A2,
                                                    const unsigned short* __restrict__ B2,
                                                    float* __restrict__ outf2,
                                                    int K, int mode) {
  int by = blockIdx.y, bx = blockIdx.x;
  const unsigned short* A = Ain;
  const unsigned short* Bw = Bwin;
  const float* bias = biasin;
  float* outf = outfin;
  if (by >= 128) {
    if (bx >= 8) return;
    A = A2; Bw = B2; bias = nullptr; outf = outf2; mode = 1; by -= 128;
  }
  __shared__ alignas(16) unsigned short As[64 * 64];
  __shared__ alignas(16) unsigned short Bs[64 * 64];
  const int t = threadIdx.x;
  const int lane = t & 63, w = t >> 6;
  const int c = lane & 15, q8 = lane >> 4;
  const int wm = (w & 1) * 32, wn = (w >> 1) * 32;
  const int m0 = by * 64, n0 = bx * 64;

  f32x4 acc[2][2];
#pragma unroll
  for (int i = 0; i < 2; ++i)
#pragma unroll
    for (int j = 0; j < 2; ++j) acc[i][j] = (f32x4){0.f, 0.f, 0.f, 0.f};

  const int srow = lane >> 3;
  const int sgr = (lane & 7) ^ srow;

  for (int k0 = 0; k0 < K; k0 += 64) {
    __syncthreads();
#pragma unroll
    for (int j = 0; j < 2; ++j) {
      int r = j * 32 + w * 8 + srow;
      GLDS16(A + (size_t)(m0 + r) * K + k0 + sgr * 8, As + (j * 256 + w * 64 + lane) * 8);
      GLDS16(Bw + (size_t)(n0 + r) * K + k0 + sgr * 8, Bs + (j * 256 + w * 64 + lane) * 8);
    }
    __syncthreads();
#pragma unroll
    for (int kk = 0; kk < 2; ++kk) {
      bf16x8 a[2], b[2];
      const int q = kk * 4 + q8;
#pragma unroll
      for (int i = 0; i < 2; ++i) {
        int r = wm + i * 16 + c;
        a[i] = *(const bf16x8*)&As[(r * 8 + (q ^ (r & 7))) * 8];
      }
#pragma unroll
      for (int j = 0; j < 2; ++j) {
        int r = wn + j * 16 + c;
        b[j] = *(const bf16x8*)&Bs[(r * 8 + (q ^ (r & 7))) * 8];
      }
#pragma unroll
      for (int i = 0; i < 2; ++i)
#pragma unroll
        for (int j = 0; j < 2; ++j)
          acc[i][j] = __builtin_amdgcn_mfma_f32_16x16x32_bf16(a[i], b[j], acc[i][j], 0, 0, 0);
    }
  }
#pragma unroll
  for (int i = 0; i < 2; ++i) {
#pragma unroll
    for (int r = 0; r < 4; ++r) {
      int m = m0 + wm + i * 16 + q8 * 4 + r;
#pragma unroll
      for (int j = 0; j < 2; ++j) {
        int n = n0 + wn + j * 16 + c;
        float val = acc[i][j][r] + (bias ? bias[n] : 0.0f);
        if (mode == 0) {
          int part = n >> 9, h = (n >> 6) & 7, dh = n & 63;
          int bb = m >> 10, l = m & 1023;
          size_t idx = (size_t)((bb * 8 + h) * 1024 + l) * 64 + dh;
          if (part == 0) {
            oq[idx] = f2b(val * QSCALE);
          } else if (part == 1) {
            ok[idx] = f2b(val);
          } else {
            union { _Float16 h; unsigned short u; } cv;
            cv.h = (_Float16)val;
            ov[idx] = cv.u;
          }
        } else if (mode == 1) {
          int h = n >> 6, dh = n & 63;
          outf[(size_t)(h * 1024 + m) * 64 + dh] = val;
        } else {
          outf[(size_t)m * 512 + n] = val;
        }
      }
    }
  }
}

// ---------------- prep2: fold (K'=k+pos, bias) + V transpose-permute (one dispatch) ----------------
__global__ __launch_bounds__(256) void prep2(unsigned short* __restrict__ kbuf,
                                             const float* __restrict__ pos,
                                             const float* __restrict__ ub,
                                             const float* __restrict__ vbb,
                                             float* __restrict__ biasout,
                                             const unsigned short* __restrict__ v,
                                             unsigned short* __restrict__ vt) {
  int b = blockIdx.x;
  int t = threadIdx.x;
  if (b < 16384) {
    int wave = t >> 6, lane = t & 63;
    int g = b * 4 + wave;  // [0, B*H*L)
    int h = (g >> 10) & 7;
    int m = g & 1023;
    float kv = b2f(kbuf[(size_t)g * 64 + lane]);
    float pv = pos[(size_t)(h * 1024 + m) * 64 + lane];
    float val = ub[h * 64 + lane] * kv + vbb[h * 64 + lane] * pv;
#pragma unroll
    for (int off = 32; off > 0; off >>= 1) val += __shfl_down(val, off);
    if (lane == 0) biasout[g] = val * QSCALE;
    kbuf[(size_t)g * 64 + lane] = f2b(kv + pv);
  } else {
    // V fp16 (b,h,l,d) -> V2 fp16 (b,h,d,perm(l)); perm: dst = ((l>>2)&3)*16 + ((l>>4)&3)*4 + (l&3)
    __shared__ unsigned short Ts[64 * 68];
    int bb = b - 16384;
    int bh = bb >> 4, lt = bb & 15;
    const unsigned short* vg = v + (size_t)bh * 65536 + lt * 4096;
#pragma unroll
    for (int s = 0; s < 4; ++s) {
      int idx = t + s * 256;
      int r = idx >> 4, c4 = (idx & 15) << 2;
      *(ushort4*)&Ts[r * 68 + c4] = *(const ushort4*)(vg + r * 64 + c4);
    }
    __syncthreads();
#pragma unroll
    for (int s = 0; s < 4; ++s) {
      int idx = t + s * 256;
      int d = idx >> 4, l4 = (idx & 15) << 2;
      ushort4 o;
      o.x = Ts[(l4 + 0) * 68 + d];
      o.y = Ts[(l4 + 1) * 68 + d];
      o.z = Ts[(l4 + 2) * 68 + d];
      o.w = Ts[(l4 + 3) * 68 + d];
      int pb = ((l4 >> 2) & 3) * 16 + ((l4 >> 4) & 3) * 4;  // l4&3 == 0
      *(ushort4*)(vt + (size_t)bh * 65536 + d * 1024 + lt * 64 + pb) = o;
    }
  }
}

// ---------------- Flash attention v5: Q-tile 128 = 4 waves x 2 query-groups, BK=128 ----------------
// S^T = K'.Q^T (bf16 x32), O^T = V^T.P^T (fp16 x16), P stays in registers.
// v5: deferred l-sum (per-lane partial, one epilogue reduction) + interleaved max shuffles.
// grid (8, 64), 256 threads; wave w owns queries {w*16+c, 64+w*16+c}.
__global__ __launch_bounds__(256, 2) void flash_mfma(const unsigned short* __restrict__ qbf,
                                                     const unsigned short* __restrict__ kbf,
                                                     const unsigned short* __restrict__ vt,
                                                     const float* __restrict__ bias,
                                                     unsigned short* __restrict__ attn_out) {
  __shared__ alignas(16) unsigned short Ks[2][64 * 64];  // key-halves; rows=key, swizzled granules over d
  __shared__ alignas(16) unsigned short Vs[2][64 * 64];  // key-halves; rows=d, swizzled granules over perm(key)
  __shared__ alignas(16) float Bls[1024];
  const int t = threadIdx.x;
  const int lane = t & 63, w = t >> 6;              // w in [0,4)
  const int c = lane & 15, q8 = lane >> 4;
  const int cc7 = c & 7;
  const int bh = blockIdx.y, qt = blockIdx.x;
  const unsigned short* qg = qbf + (size_t)bh * 65536;
  const unsigned short* kg = kbf + (size_t)bh * 65536;
  const unsigned short* vg = vt + (size_t)bh * 65536;
  const float* bg = bias + (size_t)bh * 1024;

  // stage bias once (4 KB): 256 threads x 16 B
  GLDS16(bg + t * 4, Bls + t * 4);

  // Q for both query groups, register-resident
  bf16x8 bq[2][2];
#pragma unroll
  for (int g = 0; g < 2; ++g) {
    int qlg = qt * 128 + g * 64 + w * 16 + c;
    bq[g][0] = *(const bf16x8*)(qg + (size_t)qlg * 64 + q8 * 8);
    bq[g][1] = *(const bf16x8*)(qg + (size_t)qlg * 64 + 32 + q8 * 8);
  }

  float m_st[2] = {-INFINITY, -INFINITY};
  float l_st[2] = {0.0f, 0.0f};  // per-lane PARTIAL sums (reduced across q8 in epilogue)
  f32x4 o[2][4];
#pragma unroll
  for (int g = 0; g < 2; ++g)
#pragma unroll
    for (int i = 0; i < 4; ++i) o[g][i] = (f32x4){0.f, 0.f, 0.f, 0.f};

  // staging geometry: 4 waves x 64 lanes x 2 row-sets cover 64 rows x 8 granules per array half.
  // row = w*16 + j*8 + (lane>>3); slot = lane&7; source granule = slot ^ (row&7).
  const int srow = lane >> 3;
  const int sgr = (lane & 7) ^ srow;
  const int r0 = w * 16 + srow;  // rows r0, r0+8

  // prefetch it=0 into VGPRs
  u32x4 pk[2][2], pv[2][2];
#pragma unroll
  for (int h = 0; h < 2; ++h)
#pragma unroll
    for (int j = 0; j < 2; ++j) {
      int r = r0 + j * 8;
      pk[h][j] = *(const u32x4*)(kg + (size_t)(h * 64 + r) * 64 + sgr * 8);
      pv[h][j] = *(const u32x4*)(vg + (size_t)r * 1024 + h * 64 + sgr * 8);
    }

  for (int it = 0; it < 8; ++it) {
    __syncthreads();  // prior iteration's LDS reads done
#pragma unroll
    for (int h = 0; h < 2; ++h)
#pragma unroll
      for (int j = 0; j < 2; ++j) {
        int r = r0 + j * 8;
        *(u32x4*)&Ks[h][(r * 8 + (lane & 7)) * 8] = pk[h][j];
        *(u32x4*)&Vs[h][(r * 8 + (lane & 7)) * 8] = pv[h][j];
      }
    __syncthreads();
    // prefetch next iteration (latency overlaps compute below)
    if (it < 7) {
#pragma unroll
      for (int h = 0; h < 2; ++h)
#pragma unroll
        for (int j = 0; j < 2; ++j) {
          int r = r0 + j * 8;
          pk[h][j] = *(const u32x4*)(kg + (size_t)((it + 1) * 128 + h * 64 + r) * 64 + sgr * 8);
          pv[h][j] = *(const u32x4*)(vg + (size_t)r * 1024 + (it + 1) * 128 + h * 64 + sgr * 8);
        }
    }

    // S^T for both key-halves and both query groups; K-frag + bias reads shared across groups
    f32x4 sc[2][2][4];
#pragma unroll
    for (int h = 0; h < 2; ++h) {
#pragma unroll
      for (int nt = 0; nt < 4; ++nt) {
        f32x4 ci = *(const f32x4*)&Bls[it * 128 + h * 64 + nt * 16 + q8 * 4];
        const int row = nt * 16 + c;
        bf16x8 ak0 = *(const bf16x8*)&Ks[h][(row * 8 + (q8 ^ cc7)) * 8];
        bf16x8 ak1 = *(const bf16x8*)&Ks[h][(row * 8 + ((q8 + 4) ^ cc7)) * 8];
#pragma unroll
        for (int g = 0; g < 2; ++g) {
          f32x4 z = __builtin_amdgcn_mfma_f32_16x16x32_bf16(ak0, bq[g][0], ci, 0, 0, 0);
          sc[g][h][nt] = __builtin_amdgcn_mfma_f32_16x16x32_bf16(ak1, bq[g][1], z, 0, 0, 0);
        }
      }
    }
    // online softmax: local maxima first, then INTERLEAVED cross-lane reductions
    // (the two groups' shuffle chains are independent -> their lgkm waits overlap)
    float mx[2];
#pragma unroll
    for (int g = 0; g < 2; ++g) {
      float m = sc[g][0][0][0];
#pragma unroll
      for (int h = 0; h < 2; ++h)
#pragma unroll
        for (int nt = 0; nt < 4; ++nt)
#pragma unroll
          for (int r = 0; r < 4; ++r) m = fmaxf(m, sc[g][h][nt][r]);
      mx[g] = m;
    }
    {
      float s0 = __shfl_xor(mx[0], 16);
      float s1 = __shfl_xor(mx[1], 16);
      mx[0] = fmaxf(mx[0], s0);
      mx[1] = fmaxf(mx[1], s1);
      s0 = __shfl_xor(mx[0], 32);
      s1 = __shfl_xor(mx[1], 32);
      mx[0] = fmaxf(mx[0], s0);
      mx[1] = fmaxf(mx[1], s1);
    }
    f16x4 pf[2][2][4];
#pragma unroll
    for (int g = 0; g < 2; ++g) {
      float mn = fmaxf(m_st[g], mx[g]);
      float al = __builtin_amdgcn_exp2f(m_st[g] - mn);
      float su = 0.0f;
#pragma unroll
      for (int h = 0; h < 2; ++h)
#pragma unroll
        for (int nt = 0; nt < 4; ++nt)
#pragma unroll
          for (int r = 0; r < 4; ++r) {
            float p = __builtin_amdgcn_exp2f(sc[g][h][nt][r] - mn);
            su += p;
            pf[g][h][nt][r] = (_Float16)p;
          }
      l_st[g] = l_st[g] * al + su;  // per-lane partial (al is query-uniform)
      m_st[g] = mn;
#pragma unroll
      for (int i = 0; i < 4; ++i) o[g][i] *= al;
    }
    // O^T += V^T . P^T  (x16 fp16; V-frag reads shared across groups)
#pragma unroll
    for (int i = 0; i < 4; ++i) {
      const int row = i * 16 + c;
#pragma unroll
      for (int h = 0; h < 2; ++h) {
        f16x8 v01 = *(const f16x8*)&Vs[h][(row * 8 + ((2 * q8) ^ cc7)) * 8];
        f16x8 v23 = *(const f16x8*)&Vs[h][(row * 8 + ((2 * q8 + 1) ^ cc7)) * 8];
        f16x4 a0 = {v01[0], v01[1], v01[2], v01[3]};
        f16x4 a1 = {v01[4], v01[5], v01[6], v01[7]};
        f16x4 a2 = {v23[0], v23[1], v23[2], v23[3]};
        f16x4 a3 = {v23[4], v23[5], v23[6], v23[7]};
#pragma unroll
        for (int g = 0; g < 2; ++g) {
          o[g][i] = __builtin_amdgcn_mfma_f32_16x16x16f16(a0, pf[g][h][0], o[g][i], 0, 0, 0);
          o[g][i] = __builtin_amdgcn_mfma_f32_16x16x16f16(a1, pf[g][h][1], o[g][i], 0, 0, 0);
          o[g][i] = __builtin_amdgcn_mfma_f32_16x16x16f16(a2, pf[g][h][2], o[g][i], 0, 0, 0);
          o[g][i] = __builtin_amdgcn_mfma_f32_16x16x16f16(a3, pf[g][h][3], o[g][i], 0, 0, 0);
        }
      }
    }
  }
  // epilogue: reduce the deferred l partials across q8 lanes, then write O^T
  float lt0 = l_st[0], lt1 = l_st[1];
  {
    float s0 = __shfl_xor(lt0, 16);
    float s1 = __shfl_xor(lt1, 16);
    lt0 += s0; lt1 += s1;
    s0 = __shfl_xor(lt0, 32);
    s1 = __shfl_xor(lt1, 32);
    lt0 += s0; lt1 += s1;
  }
  const int bidx = bh >> 3, h = bh & 7;
#pragma unroll
  for (int g = 0; g < 2; ++g) {
    int qlg = qt * 128 + g * 64 + w * 16 + c;
    float inv = 1.0f / (g == 0 ? lt0 : lt1);
    size_t base = (size_t)(bidx * 1024 + qlg) * 512 + h * 64;
#pragma unroll
    for (int i = 0; i < 4; ++i) {
      ushort4 ov4;
      ov4.x = f2b(o[g][i][0] * inv);
      ov4.y = f2b(o[g][i][1] * inv);
      ov4.z = f2b(o[g][i][2] * inv);
      ov4.w = f2b(o[g][i][3] * inv);
      *(ushort4*)(attn_out + base + i * 16 + q8 * 4) = ov4;
    }
  }
}

extern "C" void kernel_launch(void* const* d_in, const int* in_sizes, int n_in,
                              void* d_out, int out_size, void* d_ws, size_t ws_size,
                              hipStream_t stream) {
  const float* x      = (const float*)d_in[0];
  const float* gamma  = (const float*)d_in[1];
  const float* beta   = (const float*)d_in[2];
  const float* w_qkv  = (const float*)d_in[3];
  const float* b_qkv  = (const float*)d_in[4];
  const float* w_pos  = (const float*)d_in[5];
  const float* w_out  = (const float*)d_in[6];
  const float* b_out  = (const float*)d_in[7];
  const float* u_bias = (const float*)d_in[8];
  const float* v_bias = (const float*)d_in[9];
  float* out = (float*)d_out;

  unsigned short* wsu = (unsigned short*)d_ws;
  unsigned short* xnb   = wsu;                    // 4M ushort
  unsigned short* peb   = wsu + 4194304;          // 512K
  unsigned short* wqkvb = wsu + 4718592;          // 768K
  unsigned short* wposb = wsu + 5505024;          // 256K
  unsigned short* woutb = wsu + 5767168;          // 256K
  unsigned short* qbf   = wsu + 6291456;          // 4M (bf16, pre-scaled)
  unsigned short* kbf   = wsu + 10485760;         // 4M (K' bf16 after fold)
  unsigned short* vbf   = wsu + 14680064;         // 4M (fp16)
  unsigned short* vtb   = wsu + 18874368;         // 4M (fp16, permuted-transposed)
  unsigned short* attnb = wsu + 23068672;         // 4M (bf16)
  float* posb  = (float*)(wsu + 27262976);        // 512K floats
  float* biasb = (float*)(wsu + 28311552);        // 64K floats (pre-scaled)

  prep1<<<11520, 256, 0, stream>>>(x, gamma, beta, xnb, peb,
                                   w_qkv, wqkvb, w_pos, wposb, w_out, woutb);
  // QKV GEMM (by<128, 128x24 blocks of 64x64) + pos GEMM (by>=128, bx<8) in one dispatch
  gemm_mfma<<<dim3(24, 144), 256, 0, stream>>>(xnb, wqkvb, b_qkv, nullptr, qbf, kbf, vbf,
                                               peb, wposb, posb, 512, 0);
  prep2<<<17408, 256, 0, stream>>>(kbf, posb, u_bias, v_bias, biasb, vbf, vtb);
  flash_mfma<<<dim3(8, 64), 256, 0, stream>>>(qbf, kbf, vtb, biasb, attnb);
  gemm_mfma<<<dim3(8, 128), 256, 0, stream>>>(attnb, woutb, b_out, out, nullptr, nullptr, nullptr,
                                              nullptr, nullptr, nullptr, 512, 2);
}